// Round 1
// baseline (183.603 us; speedup 1.0000x reference)
//
#include <hip/hip_runtime.h>

typedef unsigned short u16;
typedef unsigned int   u32;
typedef short  bfrag   __attribute__((ext_vector_type(8)));   // 8 bf16 = 4 VGPR
typedef float  accfrag __attribute__((ext_vector_type(16)));  // 32x32 C/D
typedef unsigned int   u32x4 __attribute__((ext_vector_type(4)));
typedef unsigned short u16x4 __attribute__((ext_vector_type(4)));
typedef float          f32x4 __attribute__((ext_vector_type(4)));

#define B_SZ 8
#define C_SZ 512
#define T_SZ 1024
#define NH   8
#define DK   64

__device__ __forceinline__ u16 f2bf(float f) {
  u32 u = __float_as_uint(f);
  u = u + 0x7fffu + ((u >> 16) & 1u);   // RNE
  return (u16)(u >> 16);
}

__device__ __forceinline__ void permswap(u32 &a, u32 &b) {
  asm volatile("v_permlane32_swap_b32 %0, %1" : "+v"(a), "+v"(b));
}

// ---- W' = W * inv (bf16), b' = b*inv + beta - mean*inv -------------------
__global__ void prep_w(const float* __restrict__ Ws, const float* __restrict__ gam,
                       const float* __restrict__ var, u16* __restrict__ Wp) {
  int idx = blockIdx.x * 256 + threadIdx.x;      // 4*512*512
  int io = idx >> 9;                             // i*512 + o
  float inv = gam[io] * rsqrtf(var[io] + 1e-5f);
  Wp[idx] = f2bf(Ws[idx] * inv);
}

__global__ void prep_b(const float* __restrict__ bs, const float* __restrict__ gam,
                       const float* __restrict__ beta, const float* __restrict__ mean,
                       const float* __restrict__ var, float* __restrict__ bp) {
  int idx = blockIdx.x * 256 + threadIdx.x;      // 2048
  float inv = gam[idx] * rsqrtf(var[idx] + 1e-5f);
  bp[idx] = bs[idx] * inv + beta[idx] - mean[idx] * inv;
}

// ---- in[b][c][t] f32  ->  Xt[src][b][t][c] bf16 (c contiguous) -----------
__global__ void transpose_cvt(const float* __restrict__ q, const float* __restrict__ k,
                              const float* __restrict__ v, u16* __restrict__ Xt) {
  __shared__ float tile[32][33];
  int z = blockIdx.z;
  int src = z >> 3, b = z & 7;
  const float* in = (src == 0) ? q : ((src == 1) ? k : v);
  u16* out = Xt + (size_t)src * ((size_t)B_SZ * T_SZ * C_SZ);
  int t0 = blockIdx.x * 32, c0 = blockIdx.y * 32;
  int tx = threadIdx.x & 31, ty = threadIdx.x >> 5;
#pragma unroll
  for (int rr = 0; rr < 4; ++rr) {
    int c = c0 + ty + rr * 8;
    tile[ty + rr * 8][tx] = in[(((size_t)b * C_SZ + c) << 10) + t0 + tx];
  }
  __syncthreads();
#pragma unroll
  for (int rr = 0; rr < 4; ++rr) {
    int t = t0 + ty + rr * 8;
    out[(((size_t)b << 10) + t) * C_SZ + c0 + tx] = f2bf(tile[tx][ty + rr * 8]);
  }
}

// ---- mask (B,1,T,T) int32 -> bit per (t,s): word[b][t][s/32] -------------
__global__ void mask_bits(const int* __restrict__ mask, u32* __restrict__ mb) {
  int w = blockIdx.x * 256 + threadIdx.x;        // 8*1024*32 = 262144
  const int* mrow = mask + ((size_t)(w >> 5) << 10) + ((w & 31) << 5);
  u32 word = 0;
#pragma unroll
  for (int j = 0; j < 32; j += 4) {
    int4 m4 = *(const int4*)(mrow + j);
    word |= (m4.x != 0 ? 1u : 0u) << j;
    word |= (m4.y != 0 ? 1u : 0u) << (j + 1);
    word |= (m4.z != 0 ? 1u : 0u) << (j + 2);
    word |= (m4.w != 0 ? 1u : 0u) << (j + 3);
  }
  mb[w] = word;
}

// ---- new_cache = concat(key, value) f32 ----------------------------------
__global__ void cache_copy(const float* __restrict__ key, const float* __restrict__ val,
                           float* __restrict__ cache) {
  size_t gid = (size_t)blockIdx.x * 512 + threadIdx.x;   // 2,097,152
  size_t flat = gid << 2;
  int b = (int)(flat >> 20);
  int rem = (int)(flat & 1048575u);
  int c = rem >> 10;
  int t = rem & 1023;
  const float* src = (c < 512) ? (key + (((size_t)b * 512 + c) << 10) + t)
                               : (val + (((size_t)b * 512 + (c - 512)) << 10) + t);
  *(f32x4*)(cache + flat) = *(const f32x4*)src;
}

// ---- projection GEMM: Y[o][t] = sum_c W'[o][c] * Xt[t][c] + b'[o] --------
// MODE 0: bf16 out, transposed [b][t][c]   (q, k)
// MODE 1: bf16 out, natural   [b][c][t]    (v)
// MODE 2: f32  out, natural   [b][c][t]    (final out)
template <int MODE>
__launch_bounds__(256, 2)
__global__ void gemm_proj(const u16* __restrict__ Wp, const float* __restrict__ bp,
                          const u16* __restrict__ Xin, void* __restrict__ Yout) {
  __shared__ __align__(16) u16 lds[2 * 128 * 64];
  int tid = threadIdx.x;
  int b  = blockIdx.z;
  int t0 = blockIdx.x * 128;
  int o0 = blockIdx.y * 128;
  int wid = tid >> 6, lane = tid & 63;
  int ln = lane & 31, hi = lane >> 5;
  int wr = wid >> 1, wc = wid & 1;

  const char* Ag = (const char*)Wp;                                      // rows: o (1024 B stride)
  const char* Bg = (const char*)(Xin + (((size_t)b << 10) + t0) * C_SZ); // rows: t-local
  char* ldsA = (char*)lds;
  char* ldsB = (char*)lds + 16384;

  accfrag acc[2][2];
#pragma unroll
  for (int m2 = 0; m2 < 2; ++m2)
#pragma unroll
    for (int n2 = 0; n2 < 2; ++n2)
#pragma unroll
      for (int e = 0; e < 16; ++e) acc[m2][n2][e] = 0.f;

  int lin = tid * 16;
  for (int kt = 0; kt < 8; ++kt) {
    u32x4 ra[4], rb[4];
#pragma unroll
    for (int it = 0; it < 4; ++it) {
      int off = lin + it * 4096;
      int r = off >> 7, cb = off & 127;
      ra[it] = *(const u32x4*)(Ag + (size_t)(o0 + r) * 1024 + kt * 128 + cb);
      rb[it] = *(const u32x4*)(Bg + (size_t)r * 1024 + kt * 128 + cb);
    }
    __syncthreads();
#pragma unroll
    for (int it = 0; it < 4; ++it) {
      int off = lin + it * 4096;
      *(u32x4*)(ldsA + off) = ra[it];
      *(u32x4*)(ldsB + off) = rb[it];
    }
    __syncthreads();
#pragma unroll
    for (int kk = 0; kk < 4; ++kk) {
      bfrag a[2], bb[2];
#pragma unroll
      for (int m2 = 0; m2 < 2; ++m2)
        a[m2] = *(const bfrag*)(ldsA + (wr * 64 + m2 * 32 + ln) * 128 + kk * 32 + hi * 16);
#pragma unroll
      for (int n2 = 0; n2 < 2; ++n2)
        bb[n2] = *(const bfrag*)(ldsB + (wc * 64 + n2 * 32 + ln) * 128 + kk * 32 + hi * 16);
#pragma unroll
      for (int m2 = 0; m2 < 2; ++m2)
#pragma unroll
        for (int n2 = 0; n2 < 2; ++n2)
          acc[m2][n2] = __builtin_amdgcn_mfma_f32_32x32x16_bf16(a[m2], bb[n2], acc[m2][n2], 0, 0, 0);
    }
  }

#pragma unroll
  for (int m2 = 0; m2 < 2; ++m2) {
    int obase = o0 + wr * 64 + m2 * 32;
#pragma unroll
    for (int n2 = 0; n2 < 2; ++n2) {
      int t = t0 + wc * 64 + n2 * 32 + ln;
      if (MODE == 0) {
        u16* yrow = (u16*)Yout + (((size_t)b << 10) + t) * C_SZ + obase;
#pragma unroll
        for (int g = 0; g < 4; ++g) {
          u16x4 pk4;
#pragma unroll
          for (int qq = 0; qq < 4; ++qq)
            pk4[qq] = f2bf(acc[m2][n2][4 * g + qq] + bp[obase + 8 * g + 4 * hi + qq]);
          *(u16x4*)(yrow + 8 * g + 4 * hi) = pk4;
        }
      } else if (MODE == 1) {
#pragma unroll
        for (int r = 0; r < 16; ++r) {
          int o = obase + (r & 3) + 8 * (r >> 2) + 4 * hi;
          ((u16*)Yout)[(((size_t)b * C_SZ + o) << 10) + t] = f2bf(acc[m2][n2][r] + bp[o]);
        }
      } else {
#pragma unroll
        for (int r = 0; r < 16; ++r) {
          int o = obase + (r & 3) + 8 * (r >> 2) + 4 * hi;
          ((float*)Yout)[(((size_t)b * C_SZ + o) << 10) + t] = acc[m2][n2][r] + bp[o];
        }
      }
    }
  }
}

// ---- fused flash attention: S = K^T Q (scaled, masked), softmax over s, x = V P
// Qt/Kt: [b][t][c] bf16 (c contig); V: [b][c][t] bf16; out X2: [b][t][c] bf16
__launch_bounds__(256, 2)
__global__ void attn_fused(const u16* __restrict__ Qt, const u16* __restrict__ Kt,
                           const u16* __restrict__ V, const u32* __restrict__ mb,
                           u16* __restrict__ X2) {
  int bh = blockIdx.y;
  int b = bh >> 3, h = bh & 7;
  int wid = threadIdx.x >> 6, lane = threadIdx.x & 63;
  int ln = lane & 31, hi = lane >> 5;
  int t = blockIdx.x * 128 + wid * 32 + ln;

  const u16* Qrow = Qt + (((size_t)b << 10) + t) * C_SZ + h * DK;
  bfrag qf[4];
#pragma unroll
  for (int j = 0; j < 4; ++j)
    qf[j] = *(const bfrag*)(Qrow + j * 16 + hi * 8);

  const u16* Kb = Kt + ((size_t)b << 10) * C_SZ + h * DK;
  const u16* Vb = V + (((size_t)b * C_SZ + h * DK) << 10);
  const u32* mrow = mb + ((((size_t)b << 10) + t) << 5);

  float m_run = -1e30f, l_run = 0.f;
  accfrag accd[2];
#pragma unroll
  for (int m2 = 0; m2 < 2; ++m2)
#pragma unroll
    for (int e = 0; e < 16; ++e) accd[m2][e] = 0.f;

  for (int s0 = 0; s0 < T_SZ; s0 += 32) {
    accfrag S;
#pragma unroll
    for (int e = 0; e < 16; ++e) S[e] = 0.f;
    const u16* Krow = Kb + (size_t)(s0 + ln) * C_SZ;
#pragma unroll
    for (int j = 0; j < 4; ++j) {
      bfrag kf = *(const bfrag*)(Krow + j * 16 + hi * 8);
      S = __builtin_amdgcn_mfma_f32_32x32x16_bf16(kf, qf[j], S, 0, 0, 0);
    }
    u32 mw = mrow[s0 >> 5];

    // per-lane: col t fixed; regs cover 16 of 32 key-rows (other half at lane^32)
    float p[16];
    float pmax = -1e30f;
#pragma unroll
    for (int r = 0; r < 16; ++r) {
      int srow = (r & 3) + 8 * (r >> 2) + 4 * hi;
      float sc = ((mw >> srow) & 1u) ? S[r] * 0.125f : -1e30f;
      p[r] = sc;
      pmax = fmaxf(pmax, sc);
    }
    pmax = fmaxf(pmax, __shfl_xor(pmax, 32));
    float m_new = fmaxf(m_run, pmax);
    float alpha = __expf(m_run - m_new);
    float psum = 0.f;
#pragma unroll
    for (int r = 0; r < 16; ++r) {
      float e = (p[r] <= -1e29f) ? 0.f : __expf(p[r] - m_new);
      p[r] = e;
      psum += e;
    }
    psum += __shfl_xor(psum, 32);
    l_run = l_run * alpha + psum;
    m_run = m_new;
#pragma unroll
    for (int m2 = 0; m2 < 2; ++m2)
#pragma unroll
      for (int e = 0; e < 16; ++e) accd[m2][e] *= alpha;

    // P (D-layout) -> B-operand bf16 frags: 8 cvt_pk pairs + 4 permlane32_swap
    bfrag pf[2];
#pragma unroll
    for (int j2 = 0; j2 < 2; ++j2) {
      u32 A0 = (u32)f2bf(p[8 * j2 + 0]) | ((u32)f2bf(p[8 * j2 + 1]) << 16);
      u32 A1 = (u32)f2bf(p[8 * j2 + 2]) | ((u32)f2bf(p[8 * j2 + 3]) << 16);
      u32 B0 = (u32)f2bf(p[8 * j2 + 4]) | ((u32)f2bf(p[8 * j2 + 5]) << 16);
      u32 B1 = (u32)f2bf(p[8 * j2 + 6]) | ((u32)f2bf(p[8 * j2 + 7]) << 16);
      permswap(A0, B0);   // A0 -> dword0 (s: 8a+0,1), B0 -> dword2 (s: 8a+4,5)
      permswap(A1, B1);   // A1 -> dword1,          B1 -> dword3
      union { u32 u[4]; bfrag f; } pu;
      pu.u[0] = A0; pu.u[1] = A1; pu.u[2] = B0; pu.u[3] = B1;
      pf[j2] = pu.f;
    }
#pragma unroll
    for (int j2 = 0; j2 < 2; ++j2)
#pragma unroll
      for (int m2 = 0; m2 < 2; ++m2) {
        bfrag vf = *(const bfrag*)(Vb + (((size_t)(m2 * 32 + ln)) << 10) + s0 + j2 * 16 + hi * 8);
        accd[m2] = __builtin_amdgcn_mfma_f32_32x32x16_bf16(vf, pf[j2], accd[m2], 0, 0, 0);
      }
  }

  float invl = (l_run > 0.f) ? 1.f / l_run : 0.f;
  u16* Orow = X2 + (((size_t)b << 10) + t) * C_SZ + h * DK;
#pragma unroll
  for (int m2 = 0; m2 < 2; ++m2)
#pragma unroll
    for (int g = 0; g < 4; ++g) {
      u16x4 pk4;
#pragma unroll
      for (int qq = 0; qq < 4; ++qq)
        pk4[qq] = f2bf(accd[m2][4 * g + qq] * invl);
      *(u16x4*)(Orow + m2 * 32 + 8 * g + 4 * hi) = pk4;
    }
}

extern "C" void kernel_launch(void* const* d_in, const int* in_sizes, int n_in,
                              void* d_out, int out_size, void* d_ws, size_t ws_size,
                              hipStream_t stream) {
  (void)in_sizes; (void)n_in; (void)out_size; (void)ws_size;
  const float* q    = (const float*)d_in[0];
  const float* k    = (const float*)d_in[1];
  const float* v    = (const float*)d_in[2];
  const int*   mask = (const int*)d_in[3];
  const float* Ws   = (const float*)d_in[4];
  const float* bs   = (const float*)d_in[5];
  const float* gam  = (const float*)d_in[6];
  const float* beta = (const float*)d_in[7];
  const float* mean = (const float*)d_in[8];
  const float* var  = (const float*)d_in[9];

  float* out   = (float*)d_out;
  float* cache = out + (size_t)B_SZ * C_SZ * T_SZ;     // 4,194,304 floats

  const size_t ARR = (size_t)B_SZ * T_SZ * C_SZ;       // 4,194,304 elems
  char* ws = (char*)d_ws;
  u16*   Wp = (u16*)(ws);                              // 4*512*512 bf16 = 2 MB
  float* bp = (float*)(ws + 2097152);                  // 2048 f32
  u16*   Xt = (u16*)(ws + 2162688);                    // 3 * ARR bf16
  u16*   Qt = Xt + 3 * ARR;
  u16*   Kt = Qt + ARR;
  u16*   Vb = Kt + ARR;
  u16*   X2 = Vb + ARR;
  u32*   mb = (u32*)((char*)(X2 + ARR));               // 262144 words = 1 MB

  prep_w<<<4096, 256, 0, stream>>>(Ws, gam, var, Wp);
  prep_b<<<8, 256, 0, stream>>>(bs, gam, beta, mean, var, bp);
  transpose_cvt<<<dim3(32, 16, 24), 256, 0, stream>>>(q, k, v, Xt);
  mask_bits<<<1024, 256, 0, stream>>>(mask, mb);
  cache_copy<<<4096, 512, 0, stream>>>(k, v, cache);

  gemm_proj<0><<<dim3(8, 4, 8), 256, 0, stream>>>(Wp,          bp,        Xt,           (void*)Qt);
  gemm_proj<0><<<dim3(8, 4, 8), 256, 0, stream>>>(Wp + 262144, bp + 512,  Xt + ARR,     (void*)Kt);
  gemm_proj<1><<<dim3(8, 4, 8), 256, 0, stream>>>(Wp + 524288, bp + 1024, Xt + 2 * ARR, (void*)Vb);
  attn_fused<<<dim3(8, 64), 256, 0, stream>>>(Qt, Kt, Vb, mb, X2);
  gemm_proj<2><<<dim3(8, 4, 8), 256, 0, stream>>>(Wp + 786432, bp + 1536, X2,           (void*)out);
}

// Round 2
// 178.183 us; speedup vs baseline: 1.0304x; 1.0304x over previous
//
#include <hip/hip_runtime.h>

typedef unsigned short u16;
typedef unsigned int   u32;
typedef short  bfrag   __attribute__((ext_vector_type(8)));   // 8 bf16 = 4 VGPR
typedef float  accfrag __attribute__((ext_vector_type(16)));  // 32x32 C/D
typedef unsigned int   u32x4 __attribute__((ext_vector_type(4)));
typedef unsigned short u16x4 __attribute__((ext_vector_type(4)));
typedef float          f32x4 __attribute__((ext_vector_type(4)));

#define B_SZ 8
#define C_SZ 512
#define T_SZ 1024
#define NH   8
#define DK   64

__device__ __forceinline__ u16 f2bf(float f) {
  u32 u = __float_as_uint(f);
  u = u + 0x7fffu + ((u >> 16) & 1u);   // RNE
  return (u16)(u >> 16);
}

__device__ __forceinline__ u32 cvtpk(float lo, float hi) {
  u32 r;
  asm("v_cvt_pk_bf16_f32 %0, %1, %2" : "=v"(r) : "v"(lo), "v"(hi));
  return r;
}

__device__ __forceinline__ void permswap(u32 &a, u32 &b) {
  asm volatile("v_permlane32_swap_b32 %0, %1" : "+v"(a), "+v"(b));
}

// ---- W' = W * inv (bf16), b' = b*inv + beta - mean*inv -------------------
__global__ void prep_w(const float* __restrict__ Ws, const float* __restrict__ gam,
                       const float* __restrict__ var, u16* __restrict__ Wp) {
  int idx = blockIdx.x * 256 + threadIdx.x;      // 4*512*512
  int io = idx >> 9;                             // i*512 + o
  float inv = gam[io] * rsqrtf(var[io] + 1e-5f);
  Wp[idx] = f2bf(Ws[idx] * inv);
}

__global__ void prep_b(const float* __restrict__ bs, const float* __restrict__ gam,
                       const float* __restrict__ beta, const float* __restrict__ mean,
                       const float* __restrict__ var, float* __restrict__ bp) {
  int idx = blockIdx.x * 256 + threadIdx.x;      // 2048
  float inv = gam[idx] * rsqrtf(var[idx] + 1e-5f);
  bp[idx] = bs[idx] * inv + beta[idx] - mean[idx] * inv;
}

// ---- in[b][c][t] f32  ->  Xt[src][b][t][c] bf16 (c contiguous) -----------
__global__ void transpose_cvt(const float* __restrict__ q, const float* __restrict__ k,
                              const float* __restrict__ v, u16* __restrict__ Xt) {
  __shared__ float tile[32][33];
  int z = blockIdx.z;
  int src = z >> 3, b = z & 7;
  const float* in = (src == 0) ? q : ((src == 1) ? k : v);
  u16* out = Xt + (size_t)src * ((size_t)B_SZ * T_SZ * C_SZ);
  int t0 = blockIdx.x * 32, c0 = blockIdx.y * 32;
  int tx = threadIdx.x & 31, ty = threadIdx.x >> 5;
#pragma unroll
  for (int rr = 0; rr < 4; ++rr) {
    int c = c0 + ty + rr * 8;
    tile[ty + rr * 8][tx] = in[(((size_t)b * C_SZ + c) << 10) + t0 + tx];
  }
  __syncthreads();
#pragma unroll
  for (int rr = 0; rr < 4; ++rr) {
    int t = t0 + ty + rr * 8;
    out[(((size_t)b << 10) + t) * C_SZ + c0 + tx] = f2bf(tile[tx][ty + rr * 8]);
  }
}

// ---- mask (B,1,T,T) int32 -> bit per (t,s): word[b][t][s/32] -------------
__global__ void mask_bits(const int* __restrict__ mask, u32* __restrict__ mb) {
  int w = blockIdx.x * 256 + threadIdx.x;        // 8*1024*32 = 262144
  const int* mrow = mask + ((size_t)(w >> 5) << 10) + ((w & 31) << 5);
  u32 word = 0;
#pragma unroll
  for (int j = 0; j < 32; j += 4) {
    int4 m4 = *(const int4*)(mrow + j);
    word |= (m4.x != 0 ? 1u : 0u) << j;
    word |= (m4.y != 0 ? 1u : 0u) << (j + 1);
    word |= (m4.z != 0 ? 1u : 0u) << (j + 2);
    word |= (m4.w != 0 ? 1u : 0u) << (j + 3);
  }
  mb[w] = word;
}

// ---- new_cache = concat(key, value) f32 ----------------------------------
__global__ void cache_copy(const float* __restrict__ key, const float* __restrict__ val,
                           float* __restrict__ cache) {
  size_t gid = (size_t)blockIdx.x * 512 + threadIdx.x;   // 2,097,152
  size_t flat = gid << 2;
  int b = (int)(flat >> 20);
  int rem = (int)(flat & 1048575u);
  int c = rem >> 10;
  int t = rem & 1023;
  const float* src = (c < 512) ? (key + (((size_t)b * 512 + c) << 10) + t)
                               : (val + (((size_t)b * 512 + (c - 512)) << 10) + t);
  *(f32x4*)(cache + flat) = *(const f32x4*)src;
}

// ---- projection GEMM: Y[o][t] = sum_c W'[o][c] * Xt[t][c] + b'[o] --------
// MODE 0: bf16 out, transposed [b][t][c]   (q, k)
// MODE 1: bf16 out, natural   [b][c][t]    (v)
// MODE 2: f32  out, natural   [b][c][t]    (final out)
template <int MODE>
__launch_bounds__(256, 2)
__global__ void gemm_proj(const u16* __restrict__ Wp, const float* __restrict__ bp,
                          const u16* __restrict__ Xin, void* __restrict__ Yout) {
  __shared__ __align__(16) u16 lds[2 * 128 * 64];
  int tid = threadIdx.x;
  int b  = blockIdx.z;
  int t0 = blockIdx.x * 128;
  int o0 = blockIdx.y * 128;
  int wid = tid >> 6, lane = tid & 63;
  int ln = lane & 31, hi = lane >> 5;
  int wr = wid >> 1, wc = wid & 1;

  const char* Ag = (const char*)Wp;                                      // rows: o (1024 B stride)
  const char* Bg = (const char*)(Xin + (((size_t)b << 10) + t0) * C_SZ); // rows: t-local
  char* ldsA = (char*)lds;
  char* ldsB = (char*)lds + 16384;

  accfrag acc[2][2];
#pragma unroll
  for (int m2 = 0; m2 < 2; ++m2)
#pragma unroll
    for (int n2 = 0; n2 < 2; ++n2)
#pragma unroll
      for (int e = 0; e < 16; ++e) acc[m2][n2][e] = 0.f;

  int lin = tid * 16;
  for (int kt = 0; kt < 8; ++kt) {
    u32x4 ra[4], rb[4];
#pragma unroll
    for (int it = 0; it < 4; ++it) {
      int off = lin + it * 4096;
      int r = off >> 7, cb = off & 127;
      ra[it] = *(const u32x4*)(Ag + (size_t)(o0 + r) * 1024 + kt * 128 + cb);
      rb[it] = *(const u32x4*)(Bg + (size_t)r * 1024 + kt * 128 + cb);
    }
    __syncthreads();
#pragma unroll
    for (int it = 0; it < 4; ++it) {
      int off = lin + it * 4096;
      *(u32x4*)(ldsA + off) = ra[it];
      *(u32x4*)(ldsB + off) = rb[it];
    }
    __syncthreads();
#pragma unroll
    for (int kk = 0; kk < 4; ++kk) {
      bfrag a[2], bb[2];
#pragma unroll
      for (int m2 = 0; m2 < 2; ++m2)
        a[m2] = *(const bfrag*)(ldsA + (wr * 64 + m2 * 32 + ln) * 128 + kk * 32 + hi * 16);
#pragma unroll
      for (int n2 = 0; n2 < 2; ++n2)
        bb[n2] = *(const bfrag*)(ldsB + (wc * 64 + n2 * 32 + ln) * 128 + kk * 32 + hi * 16);
#pragma unroll
      for (int m2 = 0; m2 < 2; ++m2)
#pragma unroll
        for (int n2 = 0; n2 < 2; ++n2)
          acc[m2][n2] = __builtin_amdgcn_mfma_f32_32x32x16_bf16(a[m2], bb[n2], acc[m2][n2], 0, 0, 0);
    }
  }

#pragma unroll
  for (int m2 = 0; m2 < 2; ++m2) {
    int obase = o0 + wr * 64 + m2 * 32;
#pragma unroll
    for (int n2 = 0; n2 < 2; ++n2) {
      int t = t0 + wc * 64 + n2 * 32 + ln;
      if (MODE == 0) {
        u16* yrow = (u16*)Yout + (((size_t)b << 10) + t) * C_SZ + obase;
#pragma unroll
        for (int g = 0; g < 4; ++g) {
          u16x4 pk4;
#pragma unroll
          for (int qq = 0; qq < 4; ++qq)
            pk4[qq] = f2bf(acc[m2][n2][4 * g + qq] + bp[obase + 8 * g + 4 * hi + qq]);
          *(u16x4*)(yrow + 8 * g + 4 * hi) = pk4;
        }
      } else if (MODE == 1) {
#pragma unroll
        for (int r = 0; r < 16; ++r) {
          int o = obase + (r & 3) + 8 * (r >> 2) + 4 * hi;
          ((u16*)Yout)[(((size_t)b * C_SZ + o) << 10) + t] = f2bf(acc[m2][n2][r] + bp[o]);
        }
      } else {
#pragma unroll
        for (int r = 0; r < 16; ++r) {
          int o = obase + (r & 3) + 8 * (r >> 2) + 4 * hi;
          ((float*)Yout)[(((size_t)b * C_SZ + o) << 10) + t] = acc[m2][n2][r] + bp[o];
        }
      }
    }
  }
}

// ---- fused flash attention: S = K^T Q (scaled, masked), softmax over s, x = V P
// Qt/Kt: [b][t][c] bf16 (c contig); V: [b][c][t] bf16; out X2: [b][t][c] bf16
// Flat 1D grid, n = tb*64 + bh  =>  n%8 == bh%8: all 8 t-blocks of one (b,h)
// land on the same XCD -> K/V slices (256 KB) stay L2-resident per XCD.
__launch_bounds__(256, 2)
__global__ void attn_fused(const u16* __restrict__ Qt, const u16* __restrict__ Kt,
                           const u16* __restrict__ V, const u32* __restrict__ mb,
                           u16* __restrict__ X2) {
  int n = blockIdx.x;
  int bh = n & 63, tb = n >> 6;
  int b = bh >> 3, h = bh & 7;
  int wid = threadIdx.x >> 6, lane = threadIdx.x & 63;
  int ln = lane & 31, hi = lane >> 5;
  int t = tb * 128 + wid * 32 + ln;

  const u16* Qrow = Qt + (((size_t)b << 10) + t) * C_SZ + h * DK;
  bfrag qf[4];
#pragma unroll
  for (int j = 0; j < 4; ++j)
    qf[j] = *(const bfrag*)(Qrow + j * 16 + hi * 8);

  const u16* Kb = Kt + ((size_t)b << 10) * C_SZ + h * DK;
  const u16* Vb = V + (((size_t)b * C_SZ + h * DK) << 10);
  const u32* mrow = mb + ((((size_t)b << 10) + t) << 5);

  float m_run = -1e30f, l_run = 0.f;
  accfrag accd[2];
#pragma unroll
  for (int m2 = 0; m2 < 2; ++m2)
#pragma unroll
    for (int e = 0; e < 16; ++e) accd[m2][e] = 0.f;

  // prefetch K tile 0 + mask word 0
  bfrag kf[4];
  {
    const u16* Krow = Kb + (size_t)ln * C_SZ;
#pragma unroll
    for (int j = 0; j < 4; ++j)
      kf[j] = *(const bfrag*)(Krow + j * 16 + hi * 8);
  }
  u32 mw = mrow[0];

  const float SCL = 0.125f;                 // 1/sqrt(d_k)

  for (int it = 0; it < 32; ++it) {
    int s0 = it << 5;

    // V loads for THIS tile issued first: latency hides under QK^T + softmax
    bfrag vf[2][2];
#pragma unroll
    for (int j2 = 0; j2 < 2; ++j2)
#pragma unroll
      for (int m2 = 0; m2 < 2; ++m2)
        vf[j2][m2] = *(const bfrag*)(Vb + (((size_t)(m2 * 32 + ln)) << 10) + s0 + j2 * 16 + hi * 8);

    // QK^T for this tile (kf already in registers)
    accfrag S;
#pragma unroll
    for (int e = 0; e < 16; ++e) S[e] = 0.f;
#pragma unroll
    for (int j = 0; j < 4; ++j)
      S = __builtin_amdgcn_mfma_f32_32x32x16_bf16(kf[j], qf[j], S, 0, 0, 0);

    // prefetch NEXT K tile + mask word: latency hides under softmax + PV
    int sn = (s0 + 32) & 1023;              // wraps on last iter (discarded)
    bfrag kn[4];
    {
      const u16* Krow = Kb + (size_t)(sn + ln) * C_SZ;
#pragma unroll
      for (int j = 0; j < 4; ++j)
        kn[j] = *(const bfrag*)(Krow + j * 16 + hi * 8);
    }
    u32 mn = mrow[sn >> 5];

    // ---- softmax over key rows (per-lane: 16 of 32 rows; partner lane^32)
    float p[16];
#pragma unroll
    for (int r = 0; r < 16; ++r) {
      int srow = (r & 3) + 8 * (r >> 2) + 4 * hi;
      float sc = S[r] * SCL;
      p[r] = ((mw >> srow) & 1u) ? sc : -1e30f;
    }
    // tree max (depth 4)
    float q8[8], q4[4];
#pragma unroll
    for (int r = 0; r < 8; ++r) q8[r] = fmaxf(p[r], p[r + 8]);
#pragma unroll
    for (int r = 0; r < 4; ++r) q4[r] = fmaxf(q8[r], q8[r + 4]);
    float pmax = fmaxf(fmaxf(q4[0], q4[1]), fmaxf(q4[2], q4[3]));
    pmax = fmaxf(pmax, __shfl_xor(pmax, 32));

    // deferred rescale (T13): skip the alpha pass while max grows < 8
    if (__any(pmax > m_run + 8.f)) {
      float m_new = fmaxf(m_run, pmax);
      float alpha = __expf(m_run - m_new);
      l_run *= alpha;
#pragma unroll
      for (int m2 = 0; m2 < 2; ++m2)
#pragma unroll
        for (int e = 0; e < 16; ++e) accd[m2][e] *= alpha;
      m_run = m_new;
    }

#pragma unroll
    for (int r = 0; r < 16; ++r) {
      int srow = (r & 3) + 8 * (r >> 2) + 4 * hi;
      float e = __expf(p[r] - m_run);       // bounded by e^8 under defer
      p[r] = ((mw >> srow) & 1u) ? e : 0.f; // guards fully-masked m=-1e30 case
    }
    // tree sum (depth 4)
    float s8[8], s4[4];
#pragma unroll
    for (int r = 0; r < 8; ++r) s8[r] = p[r] + p[r + 8];
#pragma unroll
    for (int r = 0; r < 4; ++r) s4[r] = s8[r] + s8[r + 4];
    float psum = (s4[0] + s4[1]) + (s4[2] + s4[3]);
    psum += __shfl_xor(psum, 32);
    l_run += psum;

    // P (D-layout) -> B-operand bf16 frags: 8 cvt_pk + 4 permlane32_swap
    bfrag pf[2];
#pragma unroll
    for (int j2 = 0; j2 < 2; ++j2) {
      u32 A0 = cvtpk(p[8 * j2 + 0], p[8 * j2 + 1]);
      u32 A1 = cvtpk(p[8 * j2 + 2], p[8 * j2 + 3]);
      u32 B0 = cvtpk(p[8 * j2 + 4], p[8 * j2 + 5]);
      u32 B1 = cvtpk(p[8 * j2 + 6], p[8 * j2 + 7]);
      permswap(A0, B0);   // A0 -> dword0 (s: 8a+0,1), B0 -> dword2 (s: 8a+4,5)
      permswap(A1, B1);   // A1 -> dword1,          B1 -> dword3
      union { u32 u[4]; bfrag f; } pu;
      pu.u[0] = A0; pu.u[1] = A1; pu.u[2] = B0; pu.u[3] = B1;
      pf[j2] = pu.f;
    }
#pragma unroll
    for (int j2 = 0; j2 < 2; ++j2)
#pragma unroll
      for (int m2 = 0; m2 < 2; ++m2)
        accd[m2] = __builtin_amdgcn_mfma_f32_32x32x16_bf16(vf[j2][m2], pf[j2], accd[m2], 0, 0, 0);

    // rotate prefetched K/mask into place
#pragma unroll
    for (int j = 0; j < 4; ++j) kf[j] = kn[j];
    mw = mn;
  }

  float invl = (l_run > 0.f) ? 1.f / l_run : 0.f;
  u16* Orow = X2 + (((size_t)b << 10) + t) * C_SZ + h * DK;
#pragma unroll
  for (int m2 = 0; m2 < 2; ++m2)
#pragma unroll
    for (int g = 0; g < 4; ++g) {
      u16x4 pk4;
#pragma unroll
      for (int qq = 0; qq < 4; ++qq)
        pk4[qq] = f2bf(accd[m2][4 * g + qq] * invl);
      *(u16x4*)(Orow + m2 * 32 + 8 * g + 4 * hi) = pk4;
    }
}

extern "C" void kernel_launch(void* const* d_in, const int* in_sizes, int n_in,
                              void* d_out, int out_size, void* d_ws, size_t ws_size,
                              hipStream_t stream) {
  (void)in_sizes; (void)n_in; (void)out_size; (void)ws_size;
  const float* q    = (const float*)d_in[0];
  const float* k    = (const float*)d_in[1];
  const float* v    = (const float*)d_in[2];
  const int*   mask = (const int*)d_in[3];
  const float* Ws   = (const float*)d_in[4];
  const float* bs   = (const float*)d_in[5];
  const float* gam  = (const float*)d_in[6];
  const float* beta = (const float*)d_in[7];
  const float* mean = (const float*)d_in[8];
  const float* var  = (const float*)d_in[9];

  float* out   = (float*)d_out;
  float* cache = out + (size_t)B_SZ * C_SZ * T_SZ;     // 4,194,304 floats

  const size_t ARR = (size_t)B_SZ * T_SZ * C_SZ;       // 4,194,304 elems
  char* ws = (char*)d_ws;
  u16*   Wp = (u16*)(ws);                              // 4*512*512 bf16 = 2 MB
  float* bp = (float*)(ws + 2097152);                  // 2048 f32
  u16*   Xt = (u16*)(ws + 2162688);                    // 3 * ARR bf16
  u16*   Qt = Xt + 3 * ARR;
  u16*   Kt = Qt + ARR;
  u16*   Vb = Kt + ARR;
  u16*   X2 = Vb + ARR;
  u32*   mb = (u32*)((char*)(X2 + ARR));               // 262144 words = 1 MB

  prep_w<<<4096, 256, 0, stream>>>(Ws, gam, var, Wp);
  prep_b<<<8, 256, 0, stream>>>(bs, gam, beta, mean, var, bp);
  transpose_cvt<<<dim3(32, 16, 24), 256, 0, stream>>>(q, k, v, Xt);
  mask_bits<<<1024, 256, 0, stream>>>(mask, mb);
  cache_copy<<<4096, 512, 0, stream>>>(k, v, cache);

  gemm_proj<0><<<dim3(8, 4, 8), 256, 0, stream>>>(Wp,          bp,        Xt,           (void*)Qt);
  gemm_proj<0><<<dim3(8, 4, 8), 256, 0, stream>>>(Wp + 262144, bp + 512,  Xt + ARR,     (void*)Kt);
  gemm_proj<1><<<dim3(8, 4, 8), 256, 0, stream>>>(Wp + 524288, bp + 1024, Xt + 2 * ARR, (void*)Vb);
  attn_fused<<<512, 256, 0, stream>>>(Qt, Kt, Vb, mb, X2);
  gemm_proj<2><<<dim3(8, 4, 8), 256, 0, stream>>>(Wp + 786432, bp + 1536, X2,           (void*)out);
}

// Round 3
// 141.460 us; speedup vs baseline: 1.2979x; 1.2596x over previous
//
#include <hip/hip_runtime.h>

typedef unsigned short u16;
typedef unsigned int   u32;
typedef short  bfrag   __attribute__((ext_vector_type(8)));   // 8 bf16 = 4 VGPR
typedef float  accfrag __attribute__((ext_vector_type(16)));  // 32x32 C/D
typedef unsigned int   u32x4 __attribute__((ext_vector_type(4)));
typedef unsigned short u16x4 __attribute__((ext_vector_type(4)));
typedef float          f32x4 __attribute__((ext_vector_type(4)));

#define B_SZ 8
#define C_SZ 512
#define T_SZ 1024
#define NH   8
#define DK   64

__device__ __forceinline__ u16 f2bf(float f) {
  u32 u = __float_as_uint(f);
  u = u + 0x7fffu + ((u >> 16) & 1u);   // RNE
  return (u16)(u >> 16);
}

__device__ __forceinline__ u32 cvtpk(float lo, float hi) {
  u32 r;
  asm("v_cvt_pk_bf16_f32 %0, %1, %2" : "=v"(r) : "v"(lo), "v"(hi));
  return r;
}

__device__ __forceinline__ void permswap(u32 &a, u32 &b) {
  asm volatile("v_permlane32_swap_b32 %0, %1" : "+v"(a), "+v"(b));
}

// async global->LDS, 16B per lane; LDS dest is wave-uniform base + lane*16
__device__ __forceinline__ void gload16(const u16* g, u16* l) {
  __builtin_amdgcn_global_load_lds(
      (const __attribute__((address_space(1))) void*)g,
      (__attribute__((address_space(3))) void*)l, 16, 0, 0);
}

// ---- W' = W * inv (bf16), b' = b*inv + beta - mean*inv -------------------
__global__ void prep_w(const float* __restrict__ Ws, const float* __restrict__ gam,
                       const float* __restrict__ var, u16* __restrict__ Wp) {
  int idx = blockIdx.x * 256 + threadIdx.x;      // 4*512*512
  int io = idx >> 9;                             // i*512 + o
  float inv = gam[io] * rsqrtf(var[io] + 1e-5f);
  Wp[idx] = f2bf(Ws[idx] * inv);
}

__global__ void prep_b(const float* __restrict__ bs, const float* __restrict__ gam,
                       const float* __restrict__ beta, const float* __restrict__ mean,
                       const float* __restrict__ var, float* __restrict__ bp) {
  int idx = blockIdx.x * 256 + threadIdx.x;      // 2048
  float inv = gam[idx] * rsqrtf(var[idx] + 1e-5f);
  bp[idx] = bs[idx] * inv + beta[idx] - mean[idx] * inv;
}

// ---- in[b][c][t] f32 -> Xt[src][b][t][c] bf16; k,v also copied to cache --
__global__ void transpose_cvt(const float* __restrict__ q, const float* __restrict__ k,
                              const float* __restrict__ v, u16* __restrict__ Xt,
                              float* __restrict__ cache) {
  __shared__ float tile[32][33];
  int z = blockIdx.z;
  int src = z >> 3, b = z & 7;
  const float* in = (src == 0) ? q : ((src == 1) ? k : v);
  u16* out = Xt + (size_t)src * ((size_t)B_SZ * T_SZ * C_SZ);
  int t0 = blockIdx.x * 32, c0 = blockIdx.y * 32;
  int tx = threadIdx.x & 31, ty = threadIdx.x >> 5;
#pragma unroll
  for (int rr = 0; rr < 4; ++rr) {
    int c = c0 + ty + rr * 8;
    float val = in[(((size_t)b * C_SZ + c) << 10) + t0 + tx];
    tile[ty + rr * 8][tx] = val;
    if (src >= 1) {   // cache = concat(key, value) along channel dim
      int cc = c + (src == 2 ? 512 : 0);
      cache[((size_t)b << 20) + ((size_t)cc << 10) + t0 + tx] = val;
    }
  }
  __syncthreads();
#pragma unroll
  for (int rr = 0; rr < 4; ++rr) {
    int t = t0 + ty + rr * 8;
    out[(((size_t)b << 10) + t) * C_SZ + c0 + tx] = f2bf(tile[tx][ty + rr * 8]);
  }
}

// ---- mask (B,1,T,T) int32 -> bit-plane mbT[b][s/32][t] -------------------
__global__ void mask_bits(const int* __restrict__ mask, u32* __restrict__ mbT) {
  int w = blockIdx.x * 256 + threadIdx.x;        // 262144
  int bt = w >> 5;                               // b*1024 + t
  int st = w & 31;
  const int* mrow = mask + ((size_t)bt << 10) + (st << 5);
  u32 word = 0;
#pragma unroll
  for (int j = 0; j < 32; j += 4) {
    int4 m4 = *(const int4*)(mrow + j);
    word |= (m4.x != 0 ? 1u : 0u) << j;
    word |= (m4.y != 0 ? 1u : 0u) << (j + 1);
    word |= (m4.z != 0 ? 1u : 0u) << (j + 2);
    word |= (m4.w != 0 ? 1u : 0u) << (j + 3);
  }
  int b = bt >> 10, t = bt & 1023;
  mbT[(((size_t)b * 32 + st) << 10) + t] = word;
}

// ---- projection GEMM: Y[o][t] = sum_c W'[o][c] * Xt[t][c] + b'[o] --------
// MODE 0: bf16, MFMA-fragment-tiled layout [bh][tile32][j][lane][8]  (q, k)
// MODE 1: bf16, V-fragment-tiled layout   [bh][stile][fi][lane][8]  (v)
// MODE 2: f32  natural [b][c][t]                                    (out)
template <int MODE>
__launch_bounds__(256, 2)
__global__ void gemm_proj(const u16* __restrict__ Wp, const float* __restrict__ bp,
                          const u16* __restrict__ Xin, void* __restrict__ Yout) {
  __shared__ __align__(16) u16 lds[2 * 128 * 64];
  int tid = threadIdx.x;
  int b  = blockIdx.z;
  int t0 = blockIdx.x * 128;
  int o0 = blockIdx.y * 128;
  int wid = tid >> 6, lane = tid & 63;
  int ln = lane & 31, hi = lane >> 5;
  int wr = wid >> 1, wc = wid & 1;

  const char* Ag = (const char*)Wp;                                      // rows: o (1024 B stride)
  const char* Bg = (const char*)(Xin + (((size_t)b << 10) + t0) * C_SZ); // rows: t-local
  char* ldsA = (char*)lds;
  char* ldsB = (char*)lds + 16384;

  accfrag acc[2][2];
#pragma unroll
  for (int m2 = 0; m2 < 2; ++m2)
#pragma unroll
    for (int n2 = 0; n2 < 2; ++n2)
#pragma unroll
      for (int e = 0; e < 16; ++e) acc[m2][n2][e] = 0.f;

  int lin = tid * 16;
  for (int kt = 0; kt < 8; ++kt) {
    u32x4 ra[4], rb[4];
#pragma unroll
    for (int it = 0; it < 4; ++it) {
      int off = lin + it * 4096;
      int r = off >> 7, cb = off & 127;
      ra[it] = *(const u32x4*)(Ag + (size_t)(o0 + r) * 1024 + kt * 128 + cb);
      rb[it] = *(const u32x4*)(Bg + (size_t)r * 1024 + kt * 128 + cb);
    }
    __syncthreads();
#pragma unroll
    for (int it = 0; it < 4; ++it) {
      int off = lin + it * 4096;
      *(u32x4*)(ldsA + off) = ra[it];
      *(u32x4*)(ldsB + off) = rb[it];
    }
    __syncthreads();
#pragma unroll
    for (int kk = 0; kk < 4; ++kk) {
      bfrag a[2], bb[2];
#pragma unroll
      for (int m2 = 0; m2 < 2; ++m2)
        a[m2] = *(const bfrag*)(ldsA + (wr * 64 + m2 * 32 + ln) * 128 + kk * 32 + hi * 16);
#pragma unroll
      for (int n2 = 0; n2 < 2; ++n2)
        bb[n2] = *(const bfrag*)(ldsB + (wc * 64 + n2 * 32 + ln) * 128 + kk * 32 + hi * 16);
#pragma unroll
      for (int m2 = 0; m2 < 2; ++m2)
#pragma unroll
        for (int n2 = 0; n2 < 2; ++n2)
          acc[m2][n2] = __builtin_amdgcn_mfma_f32_32x32x16_bf16(a[m2], bb[n2], acc[m2][n2], 0, 0, 0);
    }
  }

#pragma unroll
  for (int m2 = 0; m2 < 2; ++m2) {
    int obase = o0 + wr * 64 + m2 * 32;
#pragma unroll
    for (int n2 = 0; n2 < 2; ++n2) {
      int t = t0 + wc * 64 + n2 * 32 + ln;
      if (MODE == 0) {
        // fragment layout: elem (d,t) -> [(b*8+h)*32 + t/32][dd>>4][ (t&31)+32*((dd>>3)&1) ][dd&7]
        int tt5 = t & 31, st = t >> 5;
#pragma unroll
        for (int g = 0; g < 4; ++g) {
          int d0 = obase + 8 * g + 4 * hi;
          int hh = d0 >> 6, dd = d0 & 63;
          u16x4 pk4;
#pragma unroll
          for (int qq = 0; qq < 4; ++qq)
            pk4[qq] = f2bf(acc[m2][n2][4 * g + qq] + bp[d0 + qq]);
          size_t a = ((((size_t)b * 8 + hh) * 32 + st) << 11)
                   + (size_t)((dd >> 4) * 512 + (tt5 + 32 * ((dd >> 3) & 1)) * 8 + (dd & 7));
          *(u16x4*)((u16*)Yout + a) = pk4;
        }
      } else if (MODE == 1) {
        // V-fragment layout: elem (d,s): fi=((s>>4)&1)*2+((dd>>5)&1), l=(dd&31)+((s>>3)&1)*32
        int s = t, st = s >> 5;
#pragma unroll
        for (int r = 0; r < 16; ++r) {
          int d = obase + (r & 3) + 8 * (r >> 2) + 4 * hi;
          int hh = d >> 6, dd = d & 63;
          int fi = ((s >> 4) & 1) * 2 + ((dd >> 5) & 1);
          int l  = (dd & 31) + ((s >> 3) & 1) * 32;
          ((u16*)Yout)[((((size_t)b * 8 + hh) * 32 + st) << 11)
                       + (size_t)(fi * 512 + l * 8 + (s & 7))] = f2bf(acc[m2][n2][r] + bp[d]);
        }
      } else {
#pragma unroll
        for (int r = 0; r < 16; ++r) {
          int o = obase + (r & 3) + 8 * (r >> 2) + 4 * hi;
          ((float*)Yout)[(((size_t)b * C_SZ + o) << 10) + t] = acc[m2][n2][r] + bp[o];
        }
      }
    }
  }
}

// ---- fused flash attention, fragment-layout inputs, LDS double-buffer ----
// Qf/Kf: [bh][tile32][j:4][lane:64][8] bf16; Vf: [bh][stile][fi:4][lane:64][8]
// mbT: [b][s/32][t].  4 waves/block share (b,h) -> one K/V stage per tile.
// Grid: n = tb*64 + bh  =>  n%8 == bh%8: all t-blocks of one (b,h) on one XCD.
__launch_bounds__(256, 2)
__global__ void attn_fused(const u16* __restrict__ Qf, const u16* __restrict__ Kf,
                           const u16* __restrict__ Vf, const u32* __restrict__ mbT,
                           u16* __restrict__ X2) {
  __shared__ __align__(16) u16 sK[2][2048];
  __shared__ __align__(16) u16 sV[2][2048];
  int n = blockIdx.x;
  int bh = n & 63, tb = n >> 6;
  int b = bh >> 3, h = bh & 7;
  int tid = threadIdx.x;
  int wid = tid >> 6, lane = tid & 63;
  int ln = lane & 31, hi = lane >> 5;
  int tt = tb * 4 + wid;
  int t  = tt * 32 + ln;

  // Q fragments: one coalesced 1KB load per j
  const u16* QfT = Qf + (((size_t)bh * 32 + tt) << 11);
  bfrag qf[4];
#pragma unroll
  for (int j = 0; j < 4; ++j)
    qf[j] = *(const bfrag*)(QfT + j * 512 + lane * 8);

  const u16* KfB = Kf + ((size_t)bh << 16);
  const u16* VfB = Vf + ((size_t)bh << 16);
  const u32* mcol = mbT + ((size_t)b << 15) + t;

  float m_run = -1e30f, l_run = 0.f;
  accfrag accd[2];
#pragma unroll
  for (int m2 = 0; m2 < 2; ++m2)
#pragma unroll
    for (int e = 0; e < 16; ++e) accd[m2][e] = 0.f;

  const float SCL = 0.125f;                 // 1/sqrt(d_k)
  int soff = tid * 8;                       // u16 offset: 16B per thread

  // prologue: stage tile 0 (4KB K + 4KB V), load mask word 0
  gload16(KfB + soff, &sK[0][0] + soff);
  gload16(VfB + soff, &sV[0][0] + soff);
  u32 mw = mcol[0];
  __syncthreads();

  for (int it = 0; it < 32; ++it) {
    int cur = it & 1, nxt = cur ^ 1;
    u32 mn = 0;
    if (it < 31) {   // stage next tile; latency spans the whole compute phase
      size_t tn = (size_t)(it + 1) << 11;
      gload16(KfB + tn + soff, &sK[nxt][0] + soff);
      gload16(VfB + tn + soff, &sV[nxt][0] + soff);
      mn = mcol[(it + 1) << 10];
    }

    // fragments from LDS (lane-linear -> conflict-benign b128 reads)
    bfrag kf[4], vf[4];
#pragma unroll
    for (int j = 0; j < 4; ++j) {
      kf[j] = *(const bfrag*)(&sK[cur][0] + j * 512 + lane * 8);
      vf[j] = *(const bfrag*)(&sV[cur][0] + j * 512 + lane * 8);
    }

    // QK^T
    accfrag S;
#pragma unroll
    for (int e = 0; e < 16; ++e) S[e] = 0.f;
#pragma unroll
    for (int j = 0; j < 4; ++j)
      S = __builtin_amdgcn_mfma_f32_32x32x16_bf16(kf[j], qf[j], S, 0, 0, 0);

    // ---- softmax over key rows (per-lane: 16 of 32 rows; partner lane^32)
    float p[16];
#pragma unroll
    for (int r = 0; r < 16; ++r) {
      int srow = (r & 3) + 8 * (r >> 2) + 4 * hi;
      float sc = S[r] * SCL;
      p[r] = ((mw >> srow) & 1u) ? sc : -1e30f;
    }
    float q8[8], q4[4];
#pragma unroll
    for (int r = 0; r < 8; ++r) q8[r] = fmaxf(p[r], p[r + 8]);
#pragma unroll
    for (int r = 0; r < 4; ++r) q4[r] = fmaxf(q8[r], q8[r + 4]);
    float pmax = fmaxf(fmaxf(q4[0], q4[1]), fmaxf(q4[2], q4[3]));
    pmax = fmaxf(pmax, __shfl_xor(pmax, 32));

    // deferred rescale (T13)
    if (__any(pmax > m_run + 8.f)) {
      float m_new = fmaxf(m_run, pmax);
      float alpha = __expf(m_run - m_new);
      l_run *= alpha;
#pragma unroll
      for (int m2 = 0; m2 < 2; ++m2)
#pragma unroll
        for (int e = 0; e < 16; ++e) accd[m2][e] *= alpha;
      m_run = m_new;
    }

#pragma unroll
    for (int r = 0; r < 16; ++r) {
      int srow = (r & 3) + 8 * (r >> 2) + 4 * hi;
      float e = __expf(p[r] - m_run);
      p[r] = ((mw >> srow) & 1u) ? e : 0.f;
    }
    float s8[8], s4[4];
#pragma unroll
    for (int r = 0; r < 8; ++r) s8[r] = p[r] + p[r + 8];
#pragma unroll
    for (int r = 0; r < 4; ++r) s4[r] = s8[r] + s8[r + 4];
    float psum = (s4[0] + s4[1]) + (s4[2] + s4[3]);
    psum += __shfl_xor(psum, 32);
    l_run += psum;

    // P (D-layout) -> B-operand bf16 frags: 8 cvt_pk + 4 permlane32_swap
    bfrag pf[2];
#pragma unroll
    for (int j2 = 0; j2 < 2; ++j2) {
      u32 A0 = cvtpk(p[8 * j2 + 0], p[8 * j2 + 1]);
      u32 A1 = cvtpk(p[8 * j2 + 2], p[8 * j2 + 3]);
      u32 B0 = cvtpk(p[8 * j2 + 4], p[8 * j2 + 5]);
      u32 B1 = cvtpk(p[8 * j2 + 6], p[8 * j2 + 7]);
      permswap(A0, B0);
      permswap(A1, B1);
      union { u32 u[4]; bfrag f; } pu;
      pu.u[0] = A0; pu.u[1] = A1; pu.u[2] = B0; pu.u[3] = B1;
      pf[j2] = pu.f;
    }
#pragma unroll
    for (int j2 = 0; j2 < 2; ++j2)
#pragma unroll
      for (int m2 = 0; m2 < 2; ++m2)
        accd[m2] = __builtin_amdgcn_mfma_f32_32x32x16_bf16(vf[j2 * 2 + m2], pf[j2], accd[m2], 0, 0, 0);

    __syncthreads();   // drains stage DMA (vmcnt) + LDS reads; swap buffers
    mw = mn;
  }

  float invl = (l_run > 0.f) ? 1.f / l_run : 0.f;
  u16* Orow = X2 + (((size_t)b << 10) + t) * C_SZ + h * DK;
#pragma unroll
  for (int m2 = 0; m2 < 2; ++m2)
#pragma unroll
    for (int g = 0; g < 4; ++g) {
      u16x4 pk4;
#pragma unroll
      for (int qq = 0; qq < 4; ++qq)
        pk4[qq] = f2bf(accd[m2][4 * g + qq] * invl);
      *(u16x4*)(Orow + m2 * 32 + 8 * g + 4 * hi) = pk4;
    }
}

extern "C" void kernel_launch(void* const* d_in, const int* in_sizes, int n_in,
                              void* d_out, int out_size, void* d_ws, size_t ws_size,
                              hipStream_t stream) {
  (void)in_sizes; (void)n_in; (void)out_size; (void)ws_size;
  const float* q    = (const float*)d_in[0];
  const float* k    = (const float*)d_in[1];
  const float* v    = (const float*)d_in[2];
  const int*   mask = (const int*)d_in[3];
  const float* Ws   = (const float*)d_in[4];
  const float* bs   = (const float*)d_in[5];
  const float* gam  = (const float*)d_in[6];
  const float* beta = (const float*)d_in[7];
  const float* mean = (const float*)d_in[8];
  const float* var  = (const float*)d_in[9];

  float* out   = (float*)d_out;
  float* cache = out + (size_t)B_SZ * C_SZ * T_SZ;     // 4,194,304 floats

  const size_t ARR = (size_t)B_SZ * T_SZ * C_SZ;       // 4,194,304 elems
  char* ws = (char*)d_ws;
  u16*   Wp = (u16*)(ws);                              // 4*512*512 bf16 = 2 MB
  float* bp = (float*)(ws + 2097152);                  // 2048 f32
  u16*   Xt = (u16*)(ws + 2162688);                    // 3 * ARR bf16
  u16*   Qt = Xt + 3 * ARR;                            // Qf fragment layout
  u16*   Kt = Qt + ARR;                                // Kf fragment layout
  u16*   Vb = Kt + ARR;                                // Vf fragment layout
  u16*   X2 = Vb + ARR;
  u32*   mb = (u32*)((char*)(X2 + ARR));               // 262144 words = 1 MB

  prep_w<<<4096, 256, 0, stream>>>(Ws, gam, var, Wp);
  prep_b<<<8, 256, 0, stream>>>(bs, gam, beta, mean, var, bp);
  transpose_cvt<<<dim3(32, 16, 24), 256, 0, stream>>>(q, k, v, Xt, cache);
  mask_bits<<<1024, 256, 0, stream>>>(mask, mb);

  gemm_proj<0><<<dim3(8, 4, 8), 256, 0, stream>>>(Wp,          bp,        Xt,           (void*)Qt);
  gemm_proj<0><<<dim3(8, 4, 8), 256, 0, stream>>>(Wp + 262144, bp + 512,  Xt + ARR,     (void*)Kt);
  gemm_proj<1><<<dim3(8, 4, 8), 256, 0, stream>>>(Wp + 524288, bp + 1024, Xt + 2 * ARR, (void*)Vb);
  attn_fused<<<512, 256, 0, stream>>>(Qt, Kt, Vb, mb, X2);
  gemm_proj<2><<<dim3(8, 4, 8), 256, 0, stream>>>(Wp + 786432, bp + 1536, X2,           (void*)out);
}

// Round 4
// 124.342 us; speedup vs baseline: 1.4766x; 1.1377x over previous
//
#include <hip/hip_runtime.h>

typedef unsigned short u16;
typedef unsigned int   u32;
typedef short  bfrag   __attribute__((ext_vector_type(8)));   // 8 bf16 = 4 VGPR
typedef float  accfrag __attribute__((ext_vector_type(16)));  // 32x32 C/D
typedef unsigned int   u32x4 __attribute__((ext_vector_type(4)));
typedef unsigned short u16x4 __attribute__((ext_vector_type(4)));
typedef float          f32x4 __attribute__((ext_vector_type(4)));

#define B_SZ 8
#define C_SZ 512
#define T_SZ 1024
#define NH   8
#define DK   64

// 1/sqrt(d_k) * 1/ln(2): folded into Q projection; softmax runs in exp2 domain
#define QSCL 0.18033688f

__device__ __forceinline__ u16 f2bf(float f) {
  u32 u = __float_as_uint(f);
  u = u + 0x7fffu + ((u >> 16) & 1u);   // RNE
  return (u16)(u >> 16);
}

__device__ __forceinline__ u32 cvtpk(float lo, float hi) {
  u32 r;
  asm("v_cvt_pk_bf16_f32 %0, %1, %2" : "=v"(r) : "v"(lo), "v"(hi));
  return r;
}

__device__ __forceinline__ void permswap(u32 &a, u32 &b) {
  asm volatile("v_permlane32_swap_b32 %0, %1" : "+v"(a), "+v"(b));
}

// async global->LDS, 16B per lane; LDS dest is wave-uniform base + lane*16
__device__ __forceinline__ void gload16(const u16* g, u16* l) {
  __builtin_amdgcn_global_load_lds(
      (const __attribute__((address_space(1))) void*)g,
      (__attribute__((address_space(3))) void*)l, 16, 0, 0);
}

// ---- W' = W * inv (bf16), b' = b*inv + beta - mean*inv -------------------
__global__ void prep_w(const float* __restrict__ Ws, const float* __restrict__ gam,
                       const float* __restrict__ var, u16* __restrict__ Wp) {
  int idx = blockIdx.x * 256 + threadIdx.x;      // 4*512*512
  int io = idx >> 9;                             // i*512 + o
  float inv = gam[io] * rsqrtf(var[io] + 1e-5f);
  Wp[idx] = f2bf(Ws[idx] * inv);
}

__global__ void prep_b(const float* __restrict__ bs, const float* __restrict__ gam,
                       const float* __restrict__ beta, const float* __restrict__ mean,
                       const float* __restrict__ var, float* __restrict__ bp) {
  int idx = blockIdx.x * 256 + threadIdx.x;      // 2048
  float inv = gam[idx] * rsqrtf(var[idx] + 1e-5f);
  bp[idx] = bs[idx] * inv + beta[idx] - mean[idx] * inv;
}

// ---- in[b][c][t] f32 -> Xt[src][b][t][c] bf16; k,v also copied to cache --
__global__ void transpose_cvt(const float* __restrict__ q, const float* __restrict__ k,
                              const float* __restrict__ v, u16* __restrict__ Xt,
                              float* __restrict__ cache) {
  __shared__ float tile[32][33];
  int z = blockIdx.z;
  int src = z >> 3, b = z & 7;
  const float* in = (src == 0) ? q : ((src == 1) ? k : v);
  u16* out = Xt + (size_t)src * ((size_t)B_SZ * T_SZ * C_SZ);
  int t0 = blockIdx.x * 32, c0 = blockIdx.y * 32;
  int tx = threadIdx.x & 31, ty = threadIdx.x >> 5;
#pragma unroll
  for (int rr = 0; rr < 4; ++rr) {
    int c = c0 + ty + rr * 8;
    float val = in[(((size_t)b * C_SZ + c) << 10) + t0 + tx];
    tile[ty + rr * 8][tx] = val;
    if (src >= 1) {   // cache = concat(key, value) along channel dim
      int cc = c + (src == 2 ? 512 : 0);
      cache[((size_t)b << 20) + ((size_t)cc << 10) + t0 + tx] = val;
    }
  }
  __syncthreads();
#pragma unroll
  for (int rr = 0; rr < 4; ++rr) {
    int t = t0 + ty + rr * 8;
    out[(((size_t)b << 10) + t) * C_SZ + c0 + tx] = f2bf(tile[tx][ty + rr * 8]);
  }
}

// ---- mask (B,1,T,T) int32 -> bit-plane mbT[b][s/32][t] -------------------
__global__ void mask_bits(const int* __restrict__ mask, u32* __restrict__ mbT) {
  int w = blockIdx.x * 256 + threadIdx.x;        // 262144
  int bt = w >> 5;                               // b*1024 + t
  int st = w & 31;
  const int* mrow = mask + ((size_t)bt << 10) + (st << 5);
  u32 word = 0;
#pragma unroll
  for (int j = 0; j < 32; j += 4) {
    int4 m4 = *(const int4*)(mrow + j);
    word |= (m4.x != 0 ? 1u : 0u) << j;
    word |= (m4.y != 0 ? 1u : 0u) << (j + 1);
    word |= (m4.z != 0 ? 1u : 0u) << (j + 2);
    word |= (m4.w != 0 ? 1u : 0u) << (j + 3);
  }
  int b = bt >> 10, t = bt & 1023;
  mbT[(((size_t)b * 32 + st) << 10) + t] = word;
}

// ---- fused QKV projection GEMM (one dispatch, 768 blocks = 3/CU) ---------
// src = blockIdx.z>>3: 0->Qf (scaled by QSCL), 1->Kf, 2->Vf fragment layouts
__launch_bounds__(256, 2)
__global__ void gemm_qkv(const u16* __restrict__ Wp, const float* __restrict__ bpA,
                         const u16* __restrict__ Xt,
                         u16* __restrict__ Qf, u16* __restrict__ Kf, u16* __restrict__ Vf) {
  __shared__ __align__(16) u16 lds[2 * 128 * 64];
  int tid = threadIdx.x;
  int src = blockIdx.z >> 3;
  int b   = blockIdx.z & 7;
  int t0 = blockIdx.x * 128;
  int o0 = blockIdx.y * 128;
  int wid = tid >> 6, lane = tid & 63;
  int ln = lane & 31, hi = lane >> 5;
  int wr = wid >> 1, wc = wid & 1;

  const u16* Wsrc = Wp + (size_t)src * 262144;
  const float* bp = bpA + src * 512;
  const u16* Xin  = Xt + (size_t)src * ((size_t)B_SZ * T_SZ * C_SZ);
  u16* Yout = (src == 0) ? Qf : (src == 1 ? Kf : Vf);

  const char* Ag = (const char*)Wsrc;                                    // rows: o (1024 B stride)
  const char* Bg = (const char*)(Xin + (((size_t)b << 10) + t0) * C_SZ); // rows: t-local
  char* ldsA = (char*)lds;
  char* ldsB = (char*)lds + 16384;

  accfrag acc[2][2];
#pragma unroll
  for (int m2 = 0; m2 < 2; ++m2)
#pragma unroll
    for (int n2 = 0; n2 < 2; ++n2)
#pragma unroll
      for (int e = 0; e < 16; ++e) acc[m2][n2][e] = 0.f;

  int lin = tid * 16;
  for (int kt = 0; kt < 8; ++kt) {
    u32x4 ra[4], rb[4];
#pragma unroll
    for (int it = 0; it < 4; ++it) {
      int off = lin + it * 4096;
      int r = off >> 7, cb = off & 127;
      ra[it] = *(const u32x4*)(Ag + (size_t)(o0 + r) * 1024 + kt * 128 + cb);
      rb[it] = *(const u32x4*)(Bg + (size_t)r * 1024 + kt * 128 + cb);
    }
    __syncthreads();
#pragma unroll
    for (int it = 0; it < 4; ++it) {
      int off = lin + it * 4096;
      *(u32x4*)(ldsA + off) = ra[it];
      *(u32x4*)(ldsB + off) = rb[it];
    }
    __syncthreads();
#pragma unroll
    for (int kk = 0; kk < 4; ++kk) {
      bfrag a[2], bb[2];
#pragma unroll
      for (int m2 = 0; m2 < 2; ++m2)
        a[m2] = *(const bfrag*)(ldsA + (wr * 64 + m2 * 32 + ln) * 128 + kk * 32 + hi * 16);
#pragma unroll
      for (int n2 = 0; n2 < 2; ++n2)
        bb[n2] = *(const bfrag*)(ldsB + (wc * 64 + n2 * 32 + ln) * 128 + kk * 32 + hi * 16);
#pragma unroll
      for (int m2 = 0; m2 < 2; ++m2)
#pragma unroll
        for (int n2 = 0; n2 < 2; ++n2)
          acc[m2][n2] = __builtin_amdgcn_mfma_f32_32x32x16_bf16(a[m2], bb[n2], acc[m2][n2], 0, 0, 0);
    }
  }

  float oscl = (src == 0) ? QSCL : 1.0f;
#pragma unroll
  for (int m2 = 0; m2 < 2; ++m2) {
    int obase = o0 + wr * 64 + m2 * 32;
#pragma unroll
    for (int n2 = 0; n2 < 2; ++n2) {
      int t = t0 + wc * 64 + n2 * 32 + ln;
      if (src < 2) {
        // Q/K fragment layout: [(b*8+h)*32 + t/32][dd>>4][(t&31)+32*((dd>>3)&1)][dd&7]
        int tt5 = t & 31, st = t >> 5;
#pragma unroll
        for (int g = 0; g < 4; ++g) {
          int d0 = obase + 8 * g + 4 * hi;
          int hh = d0 >> 6, dd = d0 & 63;
          u16x4 pk4;
#pragma unroll
          for (int qq = 0; qq < 4; ++qq)
            pk4[qq] = f2bf((acc[m2][n2][4 * g + qq] + bp[d0 + qq]) * oscl);
          size_t a = ((((size_t)b * 8 + hh) * 32 + st) << 11)
                   + (size_t)((dd >> 4) * 512 + (tt5 + 32 * ((dd >> 3) & 1)) * 8 + (dd & 7));
          *(u16x4*)(Yout + a) = pk4;
        }
      } else {
        // V-fragment layout: fi=((s>>4)&1)*2+((dd>>5)&1), l=(dd&31)+((s>>3)&1)*32
        int s = t, st = s >> 5;
#pragma unroll
        for (int r = 0; r < 16; ++r) {
          int d = obase + (r & 3) + 8 * (r >> 2) + 4 * hi;
          int hh = d >> 6, dd = d & 63;
          int fi = ((s >> 4) & 1) * 2 + ((dd >> 5) & 1);
          int l  = (dd & 31) + ((s >> 3) & 1) * 32;
          Yout[((((size_t)b * 8 + hh) * 32 + st) << 11)
               + (size_t)(fi * 512 + l * 8 + (s & 7))] = f2bf(acc[m2][n2][r] + bp[d]);
        }
      }
    }
  }
}

// ---- out projection GEMM: f32 natural [b][c][t] --------------------------
__launch_bounds__(256, 2)
__global__ void gemm_out(const u16* __restrict__ Wp, const float* __restrict__ bp,
                         const u16* __restrict__ Xin, float* __restrict__ Yout) {
  __shared__ __align__(16) u16 lds[2 * 128 * 64];
  int tid = threadIdx.x;
  int b  = blockIdx.z;
  int t0 = blockIdx.x * 128;
  int o0 = blockIdx.y * 128;
  int wid = tid >> 6, lane = tid & 63;
  int ln = lane & 31, hi = lane >> 5;
  int wr = wid >> 1, wc = wid & 1;

  const char* Ag = (const char*)Wp;
  const char* Bg = (const char*)(Xin + (((size_t)b << 10) + t0) * C_SZ);
  char* ldsA = (char*)lds;
  char* ldsB = (char*)lds + 16384;

  accfrag acc[2][2];
#pragma unroll
  for (int m2 = 0; m2 < 2; ++m2)
#pragma unroll
    for (int n2 = 0; n2 < 2; ++n2)
#pragma unroll
      for (int e = 0; e < 16; ++e) acc[m2][n2][e] = 0.f;

  int lin = tid * 16;
  for (int kt = 0; kt < 8; ++kt) {
    u32x4 ra[4], rb[4];
#pragma unroll
    for (int it = 0; it < 4; ++it) {
      int off = lin + it * 4096;
      int r = off >> 7, cb = off & 127;
      ra[it] = *(const u32x4*)(Ag + (size_t)(o0 + r) * 1024 + kt * 128 + cb);
      rb[it] = *(const u32x4*)(Bg + (size_t)r * 1024 + kt * 128 + cb);
    }
    __syncthreads();
#pragma unroll
    for (int it = 0; it < 4; ++it) {
      int off = lin + it * 4096;
      *(u32x4*)(ldsA + off) = ra[it];
      *(u32x4*)(ldsB + off) = rb[it];
    }
    __syncthreads();
#pragma unroll
    for (int kk = 0; kk < 4; ++kk) {
      bfrag a[2], bb[2];
#pragma unroll
      for (int m2 = 0; m2 < 2; ++m2)
        a[m2] = *(const bfrag*)(ldsA + (wr * 64 + m2 * 32 + ln) * 128 + kk * 32 + hi * 16);
#pragma unroll
      for (int n2 = 0; n2 < 2; ++n2)
        bb[n2] = *(const bfrag*)(ldsB + (wc * 64 + n2 * 32 + ln) * 128 + kk * 32 + hi * 16);
#pragma unroll
      for (int m2 = 0; m2 < 2; ++m2)
#pragma unroll
        for (int n2 = 0; n2 < 2; ++n2)
          acc[m2][n2] = __builtin_amdgcn_mfma_f32_32x32x16_bf16(a[m2], bb[n2], acc[m2][n2], 0, 0, 0);
    }
  }

#pragma unroll
  for (int m2 = 0; m2 < 2; ++m2) {
    int obase = o0 + wr * 64 + m2 * 32;
#pragma unroll
    for (int n2 = 0; n2 < 2; ++n2) {
      int t = t0 + wc * 64 + n2 * 32 + ln;
#pragma unroll
      for (int r = 0; r < 16; ++r) {
        int o = obase + (r & 3) + 8 * (r >> 2) + 4 * hi;
        Yout[(((size_t)b * C_SZ + o) << 10) + t] = acc[m2][n2][r] + bp[o];
      }
    }
  }
}

// ---- fused flash attention, in-block s-split (8 waves: grp0 s<512, grp1 s>=512)
// Qf/Kf: [bh][tile32][j:4][lane:64][8] bf16; Vf: [bh][stile][fi:4][lane:64][8]
// mbT: [b][s/32][t]. Q already scaled by 1/(sqrt(dk)*ln2) -> exp2-domain softmax.
// Grid: n = tb*64 + bh => n%8 == bh%8: all t-blocks of one (b,h) on one XCD.
__launch_bounds__(512, 4)
__global__ void attn_fused(const u16* __restrict__ Qf, const u16* __restrict__ Kf,
                           const u16* __restrict__ Vf, const u32* __restrict__ mbT,
                           u16* __restrict__ X2) {
  __shared__ __align__(16) char smem[33 * 1024];
  u16*   sK   = (u16*)smem;             // [grp:2][buf:2][2048] = 16 KB
  u16*   sV   = (u16*)(smem + 16384);   // [grp:2][buf:2][2048] = 16 KB
  float* comb = (float*)smem;           // aliases sK/sV: 4*2048 f32 = 32 KB (used post-loop)
  float* mlb  = (float*)(smem + 32768); // 4*32*2 f32 = 1 KB

  int n = blockIdx.x;
  int bh = n & 63, tb = n >> 6;
  int b = bh >> 3, h = bh & 7;
  int tid = threadIdx.x;
  int wid = tid >> 6, lane = tid & 63;
  int grp = wid >> 2, wl = wid & 3;
  int ln = lane & 31, hi = lane >> 5;
  int tt = tb * 4 + wl;
  int t  = tt * 32 + ln;

  // Q fragments: one coalesced 1KB load per j
  const u16* QfT = Qf + (((size_t)bh * 32 + tt) << 11);
  bfrag qf[4];
#pragma unroll
  for (int j = 0; j < 4; ++j)
    qf[j] = *(const bfrag*)(QfT + j * 512 + lane * 8);

  const u16* KfB = Kf + ((size_t)bh << 16);
  const u16* VfB = Vf + ((size_t)bh << 16);
  const u32* mcol = mbT + ((size_t)b << 15) + t;

  float m_run = -1e30f, l_run = 0.f;
  accfrag accd[2];
#pragma unroll
  for (int m2 = 0; m2 < 2; ++m2)
#pragma unroll
    for (int e = 0; e < 16; ++e) accd[m2][e] = 0.f;

  int gtid = tid & 255;
  int soff = gtid * 8;                      // u16 offset: 16B per thread, per 4-wave group
  u16* sKg = sK + grp * 4096;               // this group's [buf][2048]
  u16* sVg = sV + grp * 4096;
  int st0 = grp * 16;

  // prologue: stage this group's tile 0, load mask word
  gload16(KfB + ((size_t)st0 << 11) + soff, sKg + soff);
  gload16(VfB + ((size_t)st0 << 11) + soff, sVg + soff);
  u32 mw = mcol[st0 << 10];
  __syncthreads();

  for (int it = 0; it < 16; ++it) {
    int cur = it & 1, nxt = cur ^ 1;
    int st = st0 + it;
    u32 mn = 0;
    if (it < 15) {   // stage next tile; latency spans the whole compute phase
      size_t tn = (size_t)(st + 1) << 11;
      gload16(KfB + tn + soff, sKg + nxt * 2048 + soff);
      gload16(VfB + tn + soff, sVg + nxt * 2048 + soff);
      mn = mcol[(st + 1) << 10];
    }

    // fragments from LDS (lane-linear -> conflict-free b128 reads)
    bfrag kf[4], vf[4];
#pragma unroll
    for (int j = 0; j < 4; ++j) {
      kf[j] = *(const bfrag*)(sKg + cur * 2048 + j * 512 + lane * 8);
      vf[j] = *(const bfrag*)(sVg + cur * 2048 + j * 512 + lane * 8);
    }

    // QK^T (S already in log2 units: Q pre-scaled)
    accfrag S;
#pragma unroll
    for (int e = 0; e < 16; ++e) S[e] = 0.f;
#pragma unroll
    for (int j = 0; j < 4; ++j)
      S = __builtin_amdgcn_mfma_f32_32x32x16_bf16(kf[j], qf[j], S, 0, 0, 0);

    // ---- softmax over key rows (per-lane: 16 of 32 rows; partner lane^32)
    float p[16];
#pragma unroll
    for (int r = 0; r < 16; ++r) {
      int srow = (r & 3) + 8 * (r >> 2) + 4 * hi;
      p[r] = ((mw >> srow) & 1u) ? S[r] : -1e30f;
    }
    float q8[8], q4[4];
#pragma unroll
    for (int r = 0; r < 8; ++r) q8[r] = fmaxf(p[r], p[r + 8]);
#pragma unroll
    for (int r = 0; r < 4; ++r) q4[r] = fmaxf(q8[r], q8[r + 4]);
    float pmax = fmaxf(fmaxf(q4[0], q4[1]), fmaxf(q4[2], q4[3]));
    pmax = fmaxf(pmax, __shfl_xor(pmax, 32));

    // deferred rescale (T13): 8 nats = 11.54 bits
    if (__any(pmax > m_run + 11.5f)) {
      float m_new = fmaxf(m_run, pmax);
      float alpha = exp2f(m_run - m_new);
      l_run *= alpha;
#pragma unroll
      for (int m2 = 0; m2 < 2; ++m2)
#pragma unroll
        for (int e = 0; e < 16; ++e) accd[m2][e] *= alpha;
      m_run = m_new;
    }

#pragma unroll
    for (int r = 0; r < 16; ++r) {
      int srow = (r & 3) + 8 * (r >> 2) + 4 * hi;
      float e = exp2f(p[r] - m_run);
      p[r] = ((mw >> srow) & 1u) ? e : 0.f;   // guards fully-masked m=-1e30 case
    }
    float s8[8], s4[4];
#pragma unroll
    for (int r = 0; r < 8; ++r) s8[r] = p[r] + p[r + 8];
#pragma unroll
    for (int r = 0; r < 4; ++r) s4[r] = s8[r] + s8[r + 4];
    float psum = (s4[0] + s4[1]) + (s4[2] + s4[3]);
    psum += __shfl_xor(psum, 32);
    l_run += psum;

    // P (D-layout) -> B-operand bf16 frags: 8 cvt_pk + 4 permlane32_swap
    bfrag pf[2];
#pragma unroll
    for (int j2 = 0; j2 < 2; ++j2) {
      u32 A0 = cvtpk(p[8 * j2 + 0], p[8 * j2 + 1]);
      u32 A1 = cvtpk(p[8 * j2 + 2], p[8 * j2 + 3]);
      u32 B0 = cvtpk(p[8 * j2 + 4], p[8 * j2 + 5]);
      u32 B1 = cvtpk(p[8 * j2 + 6], p[8 * j2 + 7]);
      permswap(A0, B0);
      permswap(A1, B1);
      union { u32 u[4]; bfrag f; } pu;
      pu.u[0] = A0; pu.u[1] = A1; pu.u[2] = B0; pu.u[3] = B1;
      pf[j2] = pu.f;
    }
#pragma unroll
    for (int j2 = 0; j2 < 2; ++j2)
#pragma unroll
      for (int m2 = 0; m2 < 2; ++m2)
        accd[m2] = __builtin_amdgcn_mfma_f32_32x32x16_bf16(vf[j2 * 2 + m2], pf[j2], accd[m2], 0, 0, 0);

    __syncthreads();   // drains stage DMA + LDS reads; swap buffers
    mw = mn;
  }

  // ---- merge the two s-halves through LDS (comb aliases staging buffers) --
  if (grp == 1) {
#pragma unroll
    for (int m2 = 0; m2 < 2; ++m2)
#pragma unroll
      for (int e = 0; e < 16; ++e)
        comb[wl * 2048 + (m2 * 16 + e) * 64 + lane] = accd[m2][e];
    if (hi == 0) {
      mlb[(wl * 32 + ln) * 2]     = m_run;
      mlb[(wl * 32 + ln) * 2 + 1] = l_run;
    }
  }
  __syncthreads();
  if (grp == 0) {
    float m1v = mlb[(wl * 32 + ln) * 2];
    float l1v = mlb[(wl * 32 + ln) * 2 + 1];
    float M  = fmaxf(m_run, m1v);
    float w0 = exp2f(m_run - M), w1 = exp2f(m1v - M);
    float l  = l_run * w0 + l1v * w1;
    float invl = (l > 0.f) ? 1.f / l : 0.f;
    u16* Orow = X2 + (((size_t)b << 10) + t) * C_SZ + h * DK;
#pragma unroll
    for (int m2 = 0; m2 < 2; ++m2)
#pragma unroll
      for (int g = 0; g < 4; ++g) {
        u16x4 pk4;
#pragma unroll
        for (int qq = 0; qq < 4; ++qq) {
          int e = 4 * g + qq;
          float v2 = comb[wl * 2048 + (m2 * 16 + e) * 64 + lane];
          pk4[qq] = f2bf((accd[m2][e] * w0 + v2 * w1) * invl);
        }
        *(u16x4*)(Orow + m2 * 32 + 8 * g + 4 * hi) = pk4;
      }
  }
}

extern "C" void kernel_launch(void* const* d_in, const int* in_sizes, int n_in,
                              void* d_out, int out_size, void* d_ws, size_t ws_size,
                              hipStream_t stream) {
  (void)in_sizes; (void)n_in; (void)out_size; (void)ws_size;
  const float* q    = (const float*)d_in[0];
  const float* k    = (const float*)d_in[1];
  const float* v    = (const float*)d_in[2];
  const int*   mask = (const int*)d_in[3];
  const float* Ws   = (const float*)d_in[4];
  const float* bs   = (const float*)d_in[5];
  const float* gam  = (const float*)d_in[6];
  const float* beta = (const float*)d_in[7];
  const float* mean = (const float*)d_in[8];
  const float* var  = (const float*)d_in[9];

  float* out   = (float*)d_out;
  float* cache = out + (size_t)B_SZ * C_SZ * T_SZ;     // 4,194,304 floats

  const size_t ARR = (size_t)B_SZ * T_SZ * C_SZ;       // 4,194,304 elems
  char* ws = (char*)d_ws;
  u16*   Wp = (u16*)(ws);                              // 4*512*512 bf16 = 2 MB
  float* bp = (float*)(ws + 2097152);                  // 2048 f32
  u16*   Xt = (u16*)(ws + 2162688);                    // 3 * ARR bf16
  u16*   Qt = Xt + 3 * ARR;                            // Qf fragment layout
  u16*   Kt = Qt + ARR;                                // Kf fragment layout
  u16*   Vb = Kt + ARR;                                // Vf fragment layout
  u16*   X2 = Vb + ARR;
  u32*   mb = (u32*)((char*)(X2 + ARR));               // 262144 words = 1 MB

  prep_w<<<4096, 256, 0, stream>>>(Ws, gam, var, Wp);
  prep_b<<<8, 256, 0, stream>>>(bs, gam, beta, mean, var, bp);
  transpose_cvt<<<dim3(32, 16, 24), 256, 0, stream>>>(q, k, v, Xt, cache);
  mask_bits<<<1024, 256, 0, stream>>>(mask, mb);

  gemm_qkv<<<dim3(8, 4, 24), 256, 0, stream>>>(Wp, bp, Xt, Qt, Kt, Vb);
  attn_fused<<<512, 512, 0, stream>>>(Qt, Kt, Vb, mb, X2);
  gemm_out<<<dim3(8, 4, 8), 256, 0, stream>>>(Wp + 786432, bp + 1536, X2, out);
}

// Round 5
// 115.491 us; speedup vs baseline: 1.5898x; 1.0766x over previous
//
#include <hip/hip_runtime.h>

typedef unsigned short u16;
typedef unsigned int   u32;
typedef short  bfrag   __attribute__((ext_vector_type(8)));   // 8 bf16 = 4 VGPR
typedef float  accfrag __attribute__((ext_vector_type(16)));  // 32x32 C/D
typedef unsigned int   u32x4 __attribute__((ext_vector_type(4)));
typedef unsigned short u16x4 __attribute__((ext_vector_type(4)));
typedef float          f32x4 __attribute__((ext_vector_type(4)));

#define B_SZ 8
#define C_SZ 512
#define T_SZ 1024
#define NH   8
#define DK   64

// 1/sqrt(d_k) * 1/ln(2): folded into Q projection; softmax runs in exp2 domain
#define QSCL 0.18033688f

__device__ __forceinline__ u16 f2bf(float f) {
  u32 u = __float_as_uint(f);
  u = u + 0x7fffu + ((u >> 16) & 1u);   // RNE
  return (u16)(u >> 16);
}

// single v_exp_f32 (exp2f libm path is ~10 instrs — measured VALU regression r4)
__device__ __forceinline__ float fexp2(float x) {
  return __builtin_amdgcn_exp2f(x);
}

__device__ __forceinline__ u32 cvtpk(float lo, float hi) {
  u32 r;
  asm("v_cvt_pk_bf16_f32 %0, %1, %2" : "=v"(r) : "v"(lo), "v"(hi));
  return r;
}

__device__ __forceinline__ void permswap(u32 &a, u32 &b) {
  asm volatile("v_permlane32_swap_b32 %0, %1" : "+v"(a), "+v"(b));
}

// async global->LDS, 16B per lane; LDS dest is wave-uniform base + lane*16
__device__ __forceinline__ void gload16(const u16* g, u16* l) {
  __builtin_amdgcn_global_load_lds(
      (const __attribute__((address_space(1))) void*)g,
      (__attribute__((address_space(3))) void*)l, 16, 0, 0);
}

// ---- W' = W * inv (bf16), b' = b*inv + beta - mean*inv -------------------
__global__ void prep_w(const float* __restrict__ Ws, const float* __restrict__ gam,
                       const float* __restrict__ var, u16* __restrict__ Wp) {
  int idx = blockIdx.x * 256 + threadIdx.x;      // 4*512*512
  int io = idx >> 9;                             // i*512 + o
  float inv = gam[io] * rsqrtf(var[io] + 1e-5f);
  Wp[idx] = f2bf(Ws[idx] * inv);
}

__global__ void prep_b(const float* __restrict__ bs, const float* __restrict__ gam,
                       const float* __restrict__ beta, const float* __restrict__ mean,
                       const float* __restrict__ var, float* __restrict__ bp) {
  int idx = blockIdx.x * 256 + threadIdx.x;      // 2048
  float inv = gam[idx] * rsqrtf(var[idx] + 1e-5f);
  bp[idx] = bs[idx] * inv + beta[idx] - mean[idx] * inv;
}

// ---- in[b][c][t] f32 -> Xt[src][b][t][c] bf16; k,v also copied to cache --
__global__ void transpose_cvt(const float* __restrict__ q, const float* __restrict__ k,
                              const float* __restrict__ v, u16* __restrict__ Xt,
                              float* __restrict__ cache) {
  __shared__ float tile[32][33];
  int z = blockIdx.z;
  int src = z >> 3, b = z & 7;
  const float* in = (src == 0) ? q : ((src == 1) ? k : v);
  u16* out = Xt + (size_t)src * ((size_t)B_SZ * T_SZ * C_SZ);
  int t0 = blockIdx.x * 32, c0 = blockIdx.y * 32;
  int tx = threadIdx.x & 31, ty = threadIdx.x >> 5;
#pragma unroll
  for (int rr = 0; rr < 4; ++rr) {
    int c = c0 + ty + rr * 8;
    float val = in[(((size_t)b * C_SZ + c) << 10) + t0 + tx];
    tile[ty + rr * 8][tx] = val;
    if (src >= 1) {   // cache = concat(key, value) along channel dim
      int cc = c + (src == 2 ? 512 : 0);
      cache[((size_t)b << 20) + ((size_t)cc << 10) + t0 + tx] = val;
    }
  }
  __syncthreads();
#pragma unroll
  for (int rr = 0; rr < 4; ++rr) {
    int t = t0 + ty + rr * 8;
    out[(((size_t)b << 10) + t) * C_SZ + c0 + tx] = f2bf(tile[tx][ty + rr * 8]);
  }
}

// ---- mask (B,1,T,T) int32 -> bit-plane mbT[b][s/32][t] -------------------
__global__ void mask_bits(const int* __restrict__ mask, u32* __restrict__ mbT) {
  int w = blockIdx.x * 256 + threadIdx.x;        // 262144
  int bt = w >> 5;                               // b*1024 + t
  int st = w & 31;
  const int* mrow = mask + ((size_t)bt << 10) + (st << 5);
  u32 word = 0;
#pragma unroll
  for (int j = 0; j < 32; j += 4) {
    int4 m4 = *(const int4*)(mrow + j);
    word |= (m4.x != 0 ? 1u : 0u) << j;
    word |= (m4.y != 0 ? 1u : 0u) << (j + 1);
    word |= (m4.z != 0 ? 1u : 0u) << (j + 2);
    word |= (m4.w != 0 ? 1u : 0u) << (j + 3);
  }
  int b = bt >> 10, t = bt & 1023;
  mbT[(((size_t)b * 32 + st) << 10) + t] = word;
}

// ---- fused QKV projection GEMM (one dispatch, 768 blocks = 3/CU) ---------
// src = blockIdx.z>>3: 0->Qf (scaled by QSCL), 1->Kf, 2->Vf fragment layouts
__launch_bounds__(256, 2)
__global__ void gemm_qkv(const u16* __restrict__ Wp, const float* __restrict__ bpA,
                         const u16* __restrict__ Xt,
                         u16* __restrict__ Qf, u16* __restrict__ Kf, u16* __restrict__ Vf) {
  __shared__ __align__(16) u16 lds[2 * 128 * 64];
  int tid = threadIdx.x;
  int src = blockIdx.z >> 3;
  int b   = blockIdx.z & 7;
  int t0 = blockIdx.x * 128;
  int o0 = blockIdx.y * 128;
  int wid = tid >> 6, lane = tid & 63;
  int ln = lane & 31, hi = lane >> 5;
  int wr = wid >> 1, wc = wid & 1;

  const u16* Wsrc = Wp + (size_t)src * 262144;
  const float* bp = bpA + src * 512;
  const u16* Xin  = Xt + (size_t)src * ((size_t)B_SZ * T_SZ * C_SZ);
  u16* Yout = (src == 0) ? Qf : (src == 1 ? Kf : Vf);

  const char* Ag = (const char*)Wsrc;                                    // rows: o (1024 B stride)
  const char* Bg = (const char*)(Xin + (((size_t)b << 10) + t0) * C_SZ); // rows: t-local
  char* ldsA = (char*)lds;
  char* ldsB = (char*)lds + 16384;

  accfrag acc[2][2];
#pragma unroll
  for (int m2 = 0; m2 < 2; ++m2)
#pragma unroll
    for (int n2 = 0; n2 < 2; ++n2)
#pragma unroll
      for (int e = 0; e < 16; ++e) acc[m2][n2][e] = 0.f;

  int lin = tid * 16;
  for (int kt = 0; kt < 8; ++kt) {
    u32x4 ra[4], rb[4];
#pragma unroll
    for (int it = 0; it < 4; ++it) {
      int off = lin + it * 4096;
      int r = off >> 7, cb = off & 127;
      ra[it] = *(const u32x4*)(Ag + (size_t)(o0 + r) * 1024 + kt * 128 + cb);
      rb[it] = *(const u32x4*)(Bg + (size_t)r * 1024 + kt * 128 + cb);
    }
    __syncthreads();
#pragma unroll
    for (int it = 0; it < 4; ++it) {
      int off = lin + it * 4096;
      *(u32x4*)(ldsA + off) = ra[it];
      *(u32x4*)(ldsB + off) = rb[it];
    }
    __syncthreads();
#pragma unroll
    for (int kk = 0; kk < 4; ++kk) {
      bfrag a[2], bb[2];
#pragma unroll
      for (int m2 = 0; m2 < 2; ++m2)
        a[m2] = *(const bfrag*)(ldsA + (wr * 64 + m2 * 32 + ln) * 128 + kk * 32 + hi * 16);
#pragma unroll
      for (int n2 = 0; n2 < 2; ++n2)
        bb[n2] = *(const bfrag*)(ldsB + (wc * 64 + n2 * 32 + ln) * 128 + kk * 32 + hi * 16);
#pragma unroll
      for (int m2 = 0; m2 < 2; ++m2)
#pragma unroll
        for (int n2 = 0; n2 < 2; ++n2)
          acc[m2][n2] = __builtin_amdgcn_mfma_f32_32x32x16_bf16(a[m2], bb[n2], acc[m2][n2], 0, 0, 0);
    }
  }

  float oscl = (src == 0) ? QSCL : 1.0f;
#pragma unroll
  for (int m2 = 0; m2 < 2; ++m2) {
    int obase = o0 + wr * 64 + m2 * 32;
#pragma unroll
    for (int n2 = 0; n2 < 2; ++n2) {
      int t = t0 + wc * 64 + n2 * 32 + ln;
      if (src < 2) {
        // Q/K fragment layout: [(b*8+h)*32 + t/32][dd>>4][(t&31)+32*((dd>>3)&1)][dd&7]
        int tt5 = t & 31, st = t >> 5;
#pragma unroll
        for (int g = 0; g < 4; ++g) {
          int d0 = obase + 8 * g + 4 * hi;
          int hh = d0 >> 6, dd = d0 & 63;
          u16x4 pk4;
#pragma unroll
          for (int qq = 0; qq < 4; ++qq)
            pk4[qq] = f2bf((acc[m2][n2][4 * g + qq] + bp[d0 + qq]) * oscl);
          size_t a = ((((size_t)b * 8 + hh) * 32 + st) << 11)
                   + (size_t)((dd >> 4) * 512 + (tt5 + 32 * ((dd >> 3) & 1)) * 8 + (dd & 7));
          *(u16x4*)(Yout + a) = pk4;
        }
      } else {
        // V-fragment layout: fi=((s>>4)&1)*2+((dd>>5)&1), l=(dd&31)+((s>>3)&1)*32
        int s = t, st = s >> 5;
#pragma unroll
        for (int r = 0; r < 16; ++r) {
          int d = obase + (r & 3) + 8 * (r >> 2) + 4 * hi;
          int hh = d >> 6, dd = d & 63;
          int fi = ((s >> 4) & 1) * 2 + ((dd >> 5) & 1);
          int l  = (dd & 31) + ((s >> 3) & 1) * 32;
          Yout[((((size_t)b * 8 + hh) * 32 + st) << 11)
               + (size_t)(fi * 512 + l * 8 + (s & 7))] = f2bf(acc[m2][n2][r] + bp[d]);
        }
      }
    }
  }
}

// ---- out projection GEMM: f32 natural [b][c][t] --------------------------
__launch_bounds__(256, 2)
__global__ void gemm_out(const u16* __restrict__ Wp, const float* __restrict__ bp,
                         const u16* __restrict__ Xin, float* __restrict__ Yout) {
  __shared__ __align__(16) u16 lds[2 * 128 * 64];
  int tid = threadIdx.x;
  int b  = blockIdx.z;
  int t0 = blockIdx.x * 128;
  int o0 = blockIdx.y * 128;
  int wid = tid >> 6, lane = tid & 63;
  int ln = lane & 31, hi = lane >> 5;
  int wr = wid >> 1, wc = wid & 1;

  const char* Ag = (const char*)Wp;
  const char* Bg = (const char*)(Xin + (((size_t)b << 10) + t0) * C_SZ);
  char* ldsA = (char*)lds;
  char* ldsB = (char*)lds + 16384;

  accfrag acc[2][2];
#pragma unroll
  for (int m2 = 0; m2 < 2; ++m2)
#pragma unroll
    for (int n2 = 0; n2 < 2; ++n2)
#pragma unroll
      for (int e = 0; e < 16; ++e) acc[m2][n2][e] = 0.f;

  int lin = tid * 16;
  for (int kt = 0; kt < 8; ++kt) {
    u32x4 ra[4], rb[4];
#pragma unroll
    for (int it = 0; it < 4; ++it) {
      int off = lin + it * 4096;
      int r = off >> 7, cb = off & 127;
      ra[it] = *(const u32x4*)(Ag + (size_t)(o0 + r) * 1024 + kt * 128 + cb);
      rb[it] = *(const u32x4*)(Bg + (size_t)r * 1024 + kt * 128 + cb);
    }
    __syncthreads();
#pragma unroll
    for (int it = 0; it < 4; ++it) {
      int off = lin + it * 4096;
      *(u32x4*)(ldsA + off) = ra[it];
      *(u32x4*)(ldsB + off) = rb[it];
    }
    __syncthreads();
#pragma unroll
    for (int kk = 0; kk < 4; ++kk) {
      bfrag a[2], bb[2];
#pragma unroll
      for (int m2 = 0; m2 < 2; ++m2)
        a[m2] = *(const bfrag*)(ldsA + (wr * 64 + m2 * 32 + ln) * 128 + kk * 32 + hi * 16);
#pragma unroll
      for (int n2 = 0; n2 < 2; ++n2)
        bb[n2] = *(const bfrag*)(ldsB + (wc * 64 + n2 * 32 + ln) * 128 + kk * 32 + hi * 16);
#pragma unroll
      for (int m2 = 0; m2 < 2; ++m2)
#pragma unroll
        for (int n2 = 0; n2 < 2; ++n2)
          acc[m2][n2] = __builtin_amdgcn_mfma_f32_32x32x16_bf16(a[m2], bb[n2], acc[m2][n2], 0, 0, 0);
    }
  }

#pragma unroll
  for (int m2 = 0; m2 < 2; ++m2) {
    int obase = o0 + wr * 64 + m2 * 32;
#pragma unroll
    for (int n2 = 0; n2 < 2; ++n2) {
      int t = t0 + wc * 64 + n2 * 32 + ln;
#pragma unroll
      for (int r = 0; r < 16; ++r) {
        int o = obase + (r & 3) + 8 * (r >> 2) + 4 * hi;
        Yout[(((size_t)b * C_SZ + o) << 10) + t] = acc[m2][n2][r] + bp[o];
      }
    }
  }
}

// ---- fused flash attention, in-block s-split (8 waves: grp0 s<512, grp1 s>=512)
// Qf/Kf: [bh][tile32][j:4][lane:64][8] bf16; Vf: [bh][stile][fi:4][lane:64][8]
// mbT: [b][s/32][t]. Q already scaled by 1/(sqrt(dk)*ln2) -> exp2-domain softmax.
// Grid: n = tb*64 + bh => n%8 == bh%8: all t-blocks of one (b,h) on one XCD.
__launch_bounds__(512, 4)
__global__ void attn_fused(const u16* __restrict__ Qf, const u16* __restrict__ Kf,
                           const u16* __restrict__ Vf, const u32* __restrict__ mbT,
                           u16* __restrict__ X2) {
  __shared__ __align__(16) char smem[33 * 1024];
  u16*   sK   = (u16*)smem;             // [grp:2][buf:2][2048] = 16 KB
  u16*   sV   = (u16*)(smem + 16384);   // [grp:2][buf:2][2048] = 16 KB
  float* comb = (float*)smem;           // aliases sK/sV: 4*2048 f32 = 32 KB (used post-loop)
  float* mlb  = (float*)(smem + 32768); // 4*32*2 f32 = 1 KB

  int n = blockIdx.x;
  int bh = n & 63, tb = n >> 6;
  int b = bh >> 3, h = bh & 7;
  int tid = threadIdx.x;
  int wid = tid >> 6, lane = tid & 63;
  int grp = wid >> 2, wl = wid & 3;
  int ln = lane & 31, hi = lane >> 5;
  int tt = tb * 4 + wl;
  int t  = tt * 32 + ln;

  // Q fragments: one coalesced 1KB load per j
  const u16* QfT = Qf + (((size_t)bh * 32 + tt) << 11);
  bfrag qf[4];
#pragma unroll
  for (int j = 0; j < 4; ++j)
    qf[j] = *(const bfrag*)(QfT + j * 512 + lane * 8);

  const u16* KfB = Kf + ((size_t)bh << 16);
  const u16* VfB = Vf + ((size_t)bh << 16);
  const u32* mcol = mbT + ((size_t)b << 15) + t;

  // m_run floor -1e4 (not -1e30): masked scores stay -1e30, so
  // exp2(-1e30 - m_run) == +0 in HW -> no post-exp mask pass needed.
  // Fully-masked rows: m_run never raised, l_run stays 0 -> invl=0 -> zeros.
  float m_run = -1.0e4f, l_run = 0.f;
  accfrag accd[2];
#pragma unroll
  for (int m2 = 0; m2 < 2; ++m2)
#pragma unroll
    for (int e = 0; e < 16; ++e) accd[m2][e] = 0.f;

  int gtid = tid & 255;
  int soff = gtid * 8;                      // u16 offset: 16B per thread, per 4-wave group
  u16* sKg = sK + grp * 4096;               // this group's [buf][2048]
  u16* sVg = sV + grp * 4096;
  int st0 = grp * 16;

  // prologue: stage this group's tile 0, load mask word
  gload16(KfB + ((size_t)st0 << 11) + soff, sKg + soff);
  gload16(VfB + ((size_t)st0 << 11) + soff, sVg + soff);
  u32 mw = mcol[st0 << 10];
  __syncthreads();

#pragma unroll 2
  for (int it = 0; it < 16; ++it) {
    int cur = it & 1, nxt = cur ^ 1;
    int st = st0 + it;
    u32 mn = 0;
    if (it < 15) {   // stage next tile; latency spans the whole compute phase
      size_t tn = (size_t)(st + 1) << 11;
      gload16(KfB + tn + soff, sKg + nxt * 2048 + soff);
      gload16(VfB + tn + soff, sVg + nxt * 2048 + soff);
      mn = mcol[(st + 1) << 10];
    }

    // fragments from LDS (lane-linear -> conflict-free b128 reads)
    bfrag kf[4], vf[4];
#pragma unroll
    for (int j = 0; j < 4; ++j) {
      kf[j] = *(const bfrag*)(sKg + cur * 2048 + j * 512 + lane * 8);
      vf[j] = *(const bfrag*)(sVg + cur * 2048 + j * 512 + lane * 8);
    }

    // QK^T (S already in log2 units: Q pre-scaled)
    accfrag S;
#pragma unroll
    for (int e = 0; e < 16; ++e) S[e] = 0.f;
#pragma unroll
    for (int j = 0; j < 4; ++j)
      S = __builtin_amdgcn_mfma_f32_32x32x16_bf16(kf[j], qf[j], S, 0, 0, 0);

    // ---- softmax over key rows (per-lane: 16 of 32 rows; partner lane^32)
    u32 mbits = mw >> (4 * hi);          // bit positions now compile-time per r
    float p[16];
#pragma unroll
    for (int r = 0; r < 16; ++r) {
      int pos = (r & 3) + 8 * (r >> 2);  // const -> v_bfe + cndmask
      p[r] = ((mbits >> pos) & 1u) ? S[r] : -1e30f;
    }
    float q8[8], q4[4];
#pragma unroll
    for (int r = 0; r < 8; ++r) q8[r] = fmaxf(p[r], p[r + 8]);
#pragma unroll
    for (int r = 0; r < 4; ++r) q4[r] = fmaxf(q8[r], q8[r + 4]);
    float pmax = fmaxf(fmaxf(q4[0], q4[1]), fmaxf(q4[2], q4[3]));
    pmax = fmaxf(pmax, __shfl_xor(pmax, 32));

    // deferred rescale (T13): 8 nats = 11.54 bits
    if (__any(pmax > m_run + 11.5f)) {
      float m_new = fmaxf(m_run, pmax);
      float alpha = fexp2(m_run - m_new);
      l_run *= alpha;
#pragma unroll
      for (int m2 = 0; m2 < 2; ++m2)
#pragma unroll
        for (int e = 0; e < 16; ++e) accd[m2][e] *= alpha;
      m_run = m_new;
    }

#pragma unroll
    for (int r = 0; r < 16; ++r)
      p[r] = fexp2(p[r] - m_run);        // masked: exp2(-1e30) == +0
    float s8[8], s4[4];
#pragma unroll
    for (int r = 0; r < 8; ++r) s8[r] = p[r] + p[r + 8];
#pragma unroll
    for (int r = 0; r < 4; ++r) s4[r] = s8[r] + s8[r + 4];
    float psum = (s4[0] + s4[1]) + (s4[2] + s4[3]);
    psum += __shfl_xor(psum, 32);
    l_run += psum;

    // P (D-layout) -> B-operand bf16 frags: 8 cvt_pk + 4 permlane32_swap
    bfrag pf[2];
#pragma unroll
    for (int j2 = 0; j2 < 2; ++j2) {
      u32 A0 = cvtpk(p[8 * j2 + 0], p[8 * j2 + 1]);
      u32 A1 = cvtpk(p[8 * j2 + 2], p[8 * j2 + 3]);
      u32 B0 = cvtpk(p[8 * j2 + 4], p[8 * j2 + 5]);
      u32 B1 = cvtpk(p[8 * j2 + 6], p[8 * j2 + 7]);
      permswap(A0, B0);
      permswap(A1, B1);
      union { u32 u[4]; bfrag f; } pu;
      pu.u[0] = A0; pu.u[1] = A1; pu.u[2] = B0; pu.u[3] = B1;
      pf[j2] = pu.f;
    }
#pragma unroll
    for (int j2 = 0; j2 < 2; ++j2)
#pragma unroll
      for (int m2 = 0; m2 < 2; ++m2)
        accd[m2] = __builtin_amdgcn_mfma_f32_32x32x16_bf16(vf[j2 * 2 + m2], pf[j2], accd[m2], 0, 0, 0);

    __syncthreads();   // drains stage DMA + LDS reads; swap buffers
    mw = mn;
  }

  // ---- merge the two s-halves through LDS (comb aliases staging buffers) --
  if (grp == 1) {
#pragma unroll
    for (int m2 = 0; m2 < 2; ++m2)
#pragma unroll
      for (int e = 0; e < 16; ++e)
        comb[wl * 2048 + (m2 * 16 + e) * 64 + lane] = accd[m2][e];
    if (hi == 0) {
      mlb[(wl * 32 + ln) * 2]     = m_run;
      mlb[(wl * 32 + ln) * 2 + 1] = l_run;
    }
  }
  __syncthreads();
  if (grp == 0) {
    float m1v = mlb[(wl * 32 + ln) * 2];
    float l1v = mlb[(wl * 32 + ln) * 2 + 1];
    float M  = fmaxf(m_run, m1v);
    float w0 = fexp2(m_run - M), w1 = fexp2(m1v - M);
    float l  = l_run * w0 + l1v * w1;
    float invl = (l > 0.f) ? 1.f / l : 0.f;
    u16* Orow = X2 + (((size_t)b << 10) + t) * C_SZ + h * DK;
#pragma unroll
    for (int m2 = 0; m2 < 2; ++m2)
#pragma unroll
      for (int g = 0; g < 4; ++g) {
        u16x4 pk4;
#pragma unroll
        for (int qq = 0; qq < 4; ++qq) {
          int e = 4 * g + qq;
          float v2 = comb[wl * 2048 + (m2 * 16 + e) * 64 + lane];
          pk4[qq] = f2bf((accd[m2][e] * w0 + v2 * w1) * invl);
        }
        *(u16x4*)(Orow + m2 * 32 + 8 * g + 4 * hi) = pk4;
      }
  }
}

extern "C" void kernel_launch(void* const* d_in, const int* in_sizes, int n_in,
                              void* d_out, int out_size, void* d_ws, size_t ws_size,
                              hipStream_t stream) {
  (void)in_sizes; (void)n_in; (void)out_size; (void)ws_size;
  const float* q    = (const float*)d_in[0];
  const float* k    = (const float*)d_in[1];
  const float* v    = (const float*)d_in[2];
  const int*   mask = (const int*)d_in[3];
  const float* Ws   = (const float*)d_in[4];
  const float* bs   = (const float*)d_in[5];
  const float* gam  = (const float*)d_in[6];
  const float* beta = (const float*)d_in[7];
  const float* mean = (const float*)d_in[8];
  const float* var  = (const float*)d_in[9];

  float* out   = (float*)d_out;
  float* cache = out + (size_t)B_SZ * C_SZ * T_SZ;     // 4,194,304 floats

  const size_t ARR = (size_t)B_SZ * T_SZ * C_SZ;       // 4,194,304 elems
  char* ws = (char*)d_ws;
  u16*   Wp = (u16*)(ws);                              // 4*512*512 bf16 = 2 MB
  float* bp = (float*)(ws + 2097152);                  // 2048 f32
  u16*   Xt = (u16*)(ws + 2162688);                    // 3 * ARR bf16
  u16*   Qt = Xt + 3 * ARR;                            // Qf fragment layout
  u16*   Kt = Qt + ARR;                                // Kf fragment layout
  u16*   Vb = Kt + ARR;                                // Vf fragment layout
  u16*   X2 = Vb + ARR;
  u32*   mb = (u32*)((char*)(X2 + ARR));               // 262144 words = 1 MB

  prep_w<<<4096, 256, 0, stream>>>(Ws, gam, var, Wp);
  prep_b<<<8, 256, 0, stream>>>(bs, gam, beta, mean, var, bp);
  transpose_cvt<<<dim3(32, 16, 24), 256, 0, stream>>>(q, k, v, Xt, cache);
  mask_bits<<<1024, 256, 0, stream>>>(mask, mb);

  gemm_qkv<<<dim3(8, 4, 24), 256, 0, stream>>>(Wp, bp, Xt, Qt, Kt, Vb);
  attn_fused<<<512, 512, 0, stream>>>(Qt, Kt, Vb, mb, X2);
  gemm_out<<<dim3(8, 4, 8), 256, 0, stream>>>(Wp + 786432, bp + 1536, X2, out);
}

// Round 6
// 97.628 us; speedup vs baseline: 1.8806x; 1.1830x over previous
//
#include <hip/hip_runtime.h>

typedef unsigned short u16;
typedef unsigned int   u32;
typedef short  bfrag   __attribute__((ext_vector_type(8)));   // 8 bf16 = 4 VGPR
typedef float  accfrag __attribute__((ext_vector_type(16)));  // 32x32 C/D
typedef unsigned int   u32x4 __attribute__((ext_vector_type(4)));
typedef unsigned short u16x4 __attribute__((ext_vector_type(4)));
typedef float          f32x4 __attribute__((ext_vector_type(4)));

#define B_SZ 8
#define C_SZ 512
#define T_SZ 1024
#define NH   8
#define DK   64

// 1/sqrt(d_k) * 1/ln(2): folded into Q projection; softmax runs in exp2 domain
#define QSCL 0.18033688f

__device__ __forceinline__ u16 f2bf(float f) {
  u32 u = __float_as_uint(f);
  u = u + 0x7fffu + ((u >> 16) & 1u);   // RNE
  return (u16)(u >> 16);
}

// single v_exp_f32 (exp2f libm path is ~10 instrs — measured VALU regression r4)
__device__ __forceinline__ float fexp2(float x) {
  return __builtin_amdgcn_exp2f(x);
}

__device__ __forceinline__ u32 cvtpk(float lo, float hi) {
  u32 r;
  asm("v_cvt_pk_bf16_f32 %0, %1, %2" : "=v"(r) : "v"(lo), "v"(hi));
  return r;
}

__device__ __forceinline__ void permswap(u32 &a, u32 &b) {
  asm volatile("v_permlane32_swap_b32 %0, %1" : "+v"(a), "+v"(b));
}

// async global->LDS, 16B per lane; LDS dest is wave-uniform base + lane*16
__device__ __forceinline__ void gload16(const u16* g, u16* l) {
  __builtin_amdgcn_global_load_lds(
      (const __attribute__((address_space(1))) void*)g,
      (__attribute__((address_space(3))) void*)l, 16, 0, 0);
}

// ---- W' = W * inv (bf16), b' = b*inv + beta - mean*inv -------------------
__global__ void prep_w(const float* __restrict__ Ws, const float* __restrict__ gam,
                       const float* __restrict__ var, u16* __restrict__ Wp) {
  int idx = blockIdx.x * 256 + threadIdx.x;      // 4*512*512
  int io = idx >> 9;                             // i*512 + o
  float inv = gam[io] * rsqrtf(var[io] + 1e-5f);
  Wp[idx] = f2bf(Ws[idx] * inv);
}

__global__ void prep_b(const float* __restrict__ bs, const float* __restrict__ gam,
                       const float* __restrict__ beta, const float* __restrict__ mean,
                       const float* __restrict__ var, float* __restrict__ bp) {
  int idx = blockIdx.x * 256 + threadIdx.x;      // 2048
  float inv = gam[idx] * rsqrtf(var[idx] + 1e-5f);
  bp[idx] = bs[idx] * inv + beta[idx] - mean[idx] * inv;
}

// ---- in[b][c][t] f32 -> Xt[src][b][t][c] bf16; k,v also copied to cache --
__global__ void transpose_cvt(const float* __restrict__ q, const float* __restrict__ k,
                              const float* __restrict__ v, u16* __restrict__ Xt,
                              float* __restrict__ cache) {
  __shared__ float tile[32][33];
  int z = blockIdx.z;
  int src = z >> 3, b = z & 7;
  const float* in = (src == 0) ? q : ((src == 1) ? k : v);
  u16* out = Xt + (size_t)src * ((size_t)B_SZ * T_SZ * C_SZ);
  int t0 = blockIdx.x * 32, c0 = blockIdx.y * 32;
  int tx = threadIdx.x & 31, ty = threadIdx.x >> 5;
#pragma unroll
  for (int rr = 0; rr < 4; ++rr) {
    int c = c0 + ty + rr * 8;
    float val = in[(((size_t)b * C_SZ + c) << 10) + t0 + tx];
    tile[ty + rr * 8][tx] = val;
    if (src >= 1) {   // cache = concat(key, value) along channel dim
      int cc = c + (src == 2 ? 512 : 0);
      cache[((size_t)b << 20) + ((size_t)cc << 10) + t0 + tx] = val;
    }
  }
  __syncthreads();
#pragma unroll
  for (int rr = 0; rr < 4; ++rr) {
    int t = t0 + ty + rr * 8;
    out[(((size_t)b << 10) + t) * C_SZ + c0 + tx] = f2bf(tile[tx][ty + rr * 8]);
  }
}

// ---- mask (B,1,T,T) int32 -> bit-plane mbT[b][s/32][t] -------------------
__global__ void mask_bits(const int* __restrict__ mask, u32* __restrict__ mbT) {
  int w = blockIdx.x * 256 + threadIdx.x;        // 262144
  int bt = w >> 5;                               // b*1024 + t
  int st = w & 31;
  const int* mrow = mask + ((size_t)bt << 10) + (st << 5);
  u32 word = 0;
#pragma unroll
  for (int j = 0; j < 32; j += 4) {
    int4 m4 = *(const int4*)(mrow + j);
    word |= (m4.x != 0 ? 1u : 0u) << j;
    word |= (m4.y != 0 ? 1u : 0u) << (j + 1);
    word |= (m4.z != 0 ? 1u : 0u) << (j + 2);
    word |= (m4.w != 0 ? 1u : 0u) << (j + 3);
  }
  int b = bt >> 10, t = bt & 1023;
  mbT[(((size_t)b * 32 + st) << 10) + t] = word;
}

// ---- fused QKV projection GEMM (one dispatch, 768 blocks = 3/CU) ---------
// src = blockIdx.z>>3: 0->Qf (scaled by QSCL), 1->Kf, 2->Vf fragment layouts
// K-loop: reg-prefetch pipeline (load kt+1 under compute kt) + XOR-swizzled LDS
__launch_bounds__(256, 2)
__global__ void gemm_qkv(const u16* __restrict__ Wp, const float* __restrict__ bpA,
                         const u16* __restrict__ Xt,
                         u16* __restrict__ Qf, u16* __restrict__ Kf, u16* __restrict__ Vf) {
  __shared__ __align__(16) u16 lds[2 * 128 * 64];
  int tid = threadIdx.x;
  int src = blockIdx.z >> 3;
  int b   = blockIdx.z & 7;
  int t0 = blockIdx.x * 128;
  int o0 = blockIdx.y * 128;
  int wid = tid >> 6, lane = tid & 63;
  int ln = lane & 31, hi = lane >> 5;
  int wr = wid >> 1, wc = wid & 1;

  const u16* Wsrc = Wp + (size_t)src * 262144;
  const float* bp = bpA + src * 512;
  const u16* Xin  = Xt + (size_t)src * ((size_t)B_SZ * T_SZ * C_SZ);
  u16* Yout = (src == 0) ? Qf : (src == 1 ? Kf : Vf);

  const char* Ag = (const char*)Wsrc;                                    // rows: o (1024 B stride)
  const char* Bg = (const char*)(Xin + (((size_t)b << 10) + t0) * C_SZ); // rows: t-local
  char* ldsA = (char*)lds;
  char* ldsB = (char*)lds + 16384;

  accfrag acc[2][2];
#pragma unroll
  for (int m2 = 0; m2 < 2; ++m2)
#pragma unroll
    for (int n2 = 0; n2 < 2; ++n2)
#pragma unroll
      for (int e = 0; e < 16; ++e) acc[m2][n2][e] = 0.f;

  int lin = tid * 16;
  u32x4 ra[4], rb[4];
#pragma unroll
  for (int it = 0; it < 4; ++it) {   // prologue: load kt=0
    int off = lin + it * 4096;
    int r = off >> 7, cb = off & 127;
    ra[it] = *(const u32x4*)(Ag + (size_t)(o0 + r) * 1024 + cb);
    rb[it] = *(const u32x4*)(Bg + (size_t)r * 1024 + cb);
  }

  for (int kt = 0; kt < 8; ++kt) {
    __syncthreads();   // LDS free (previous compute done by all waves)
#pragma unroll
    for (int it = 0; it < 4; ++it) {
      int off = lin + it * 4096;
      int swz = off ^ (((off >> 7) & 7) << 4);   // bank swizzle (G4)
      *(u32x4*)(ldsA + swz) = ra[it];
      *(u32x4*)(ldsB + swz) = rb[it];
    }
    __syncthreads();   // LDS ready
    if (kt < 7) {      // prefetch kt+1; latency hides under the MFMA cluster
#pragma unroll
      for (int it = 0; it < 4; ++it) {
        int off = lin + it * 4096;
        int r = off >> 7, cb = off & 127;
        ra[it] = *(const u32x4*)(Ag + (size_t)(o0 + r) * 1024 + (kt + 1) * 128 + cb);
        rb[it] = *(const u32x4*)(Bg + (size_t)r * 1024 + (kt + 1) * 128 + cb);
      }
    }
#pragma unroll
    for (int kk = 0; kk < 4; ++kk) {
      int csw = (kk * 32 + hi * 16) ^ ((ln & 7) << 4);   // swizzled col
      bfrag a[2], bb[2];
#pragma unroll
      for (int m2 = 0; m2 < 2; ++m2)
        a[m2] = *(const bfrag*)(ldsA + (wr * 64 + m2 * 32 + ln) * 128 + csw);
#pragma unroll
      for (int n2 = 0; n2 < 2; ++n2)
        bb[n2] = *(const bfrag*)(ldsB + (wc * 64 + n2 * 32 + ln) * 128 + csw);
#pragma unroll
      for (int m2 = 0; m2 < 2; ++m2)
#pragma unroll
        for (int n2 = 0; n2 < 2; ++n2)
          acc[m2][n2] = __builtin_amdgcn_mfma_f32_32x32x16_bf16(a[m2], bb[n2], acc[m2][n2], 0, 0, 0);
    }
  }

  float oscl = (src == 0) ? QSCL : 1.0f;
#pragma unroll
  for (int m2 = 0; m2 < 2; ++m2) {
    int obase = o0 + wr * 64 + m2 * 32;
#pragma unroll
    for (int n2 = 0; n2 < 2; ++n2) {
      int t = t0 + wc * 64 + n2 * 32 + ln;
      if (src < 2) {
        // Q/K fragment layout: [(b*8+h)*32 + t/32][dd>>4][(t&31)+32*((dd>>3)&1)][dd&7]
        int tt5 = t & 31, st = t >> 5;
#pragma unroll
        for (int g = 0; g < 4; ++g) {
          int d0 = obase + 8 * g + 4 * hi;
          int hh = d0 >> 6, dd = d0 & 63;
          u16x4 pk4;
#pragma unroll
          for (int qq = 0; qq < 4; ++qq)
            pk4[qq] = f2bf((acc[m2][n2][4 * g + qq] + bp[d0 + qq]) * oscl);
          size_t a = ((((size_t)b * 8 + hh) * 32 + st) << 11)
                   + (size_t)((dd >> 4) * 512 + (tt5 + 32 * ((dd >> 3) & 1)) * 8 + (dd & 7));
          *(u16x4*)(Yout + a) = pk4;
        }
      } else {
        // V-fragment layout: fi=((s>>4)&1)*2+((dd>>5)&1), l=(dd&31)+((s>>3)&1)*32
        int s = t, st = s >> 5;
#pragma unroll
        for (int r = 0; r < 16; ++r) {
          int d = obase + (r & 3) + 8 * (r >> 2) + 4 * hi;
          int hh = d >> 6, dd = d & 63;
          int fi = ((s >> 4) & 1) * 2 + ((dd >> 5) & 1);
          int l  = (dd & 31) + ((s >> 3) & 1) * 32;
          Yout[((((size_t)b * 8 + hh) * 32 + st) << 11)
               + (size_t)(fi * 512 + l * 8 + (s & 7))] = f2bf(acc[m2][n2][r] + bp[d]);
        }
      }
    }
  }
}

// ---- out projection GEMM: f32 natural [b][c][t] --------------------------
__launch_bounds__(256, 2)
__global__ void gemm_out(const u16* __restrict__ Wp, const float* __restrict__ bp,
                         const u16* __restrict__ Xin, float* __restrict__ Yout) {
  __shared__ __align__(16) u16 lds[2 * 128 * 64];
  int tid = threadIdx.x;
  int b  = blockIdx.z;
  int t0 = blockIdx.x * 128;
  int o0 = blockIdx.y * 128;
  int wid = tid >> 6, lane = tid & 63;
  int ln = lane & 31, hi = lane >> 5;
  int wr = wid >> 1, wc = wid & 1;

  const char* Ag = (const char*)Wp;
  const char* Bg = (const char*)(Xin + (((size_t)b << 10) + t0) * C_SZ);
  char* ldsA = (char*)lds;
  char* ldsB = (char*)lds + 16384;

  accfrag acc[2][2];
#pragma unroll
  for (int m2 = 0; m2 < 2; ++m2)
#pragma unroll
    for (int n2 = 0; n2 < 2; ++n2)
#pragma unroll
      for (int e = 0; e < 16; ++e) acc[m2][n2][e] = 0.f;

  int lin = tid * 16;
  u32x4 ra[4], rb[4];
#pragma unroll
  for (int it = 0; it < 4; ++it) {   // prologue: load kt=0
    int off = lin + it * 4096;
    int r = off >> 7, cb = off & 127;
    ra[it] = *(const u32x4*)(Ag + (size_t)(o0 + r) * 1024 + cb);
    rb[it] = *(const u32x4*)(Bg + (size_t)r * 1024 + cb);
  }

  for (int kt = 0; kt < 8; ++kt) {
    __syncthreads();
#pragma unroll
    for (int it = 0; it < 4; ++it) {
      int off = lin + it * 4096;
      int swz = off ^ (((off >> 7) & 7) << 4);
      *(u32x4*)(ldsA + swz) = ra[it];
      *(u32x4*)(ldsB + swz) = rb[it];
    }
    __syncthreads();
    if (kt < 7) {
#pragma unroll
      for (int it = 0; it < 4; ++it) {
        int off = lin + it * 4096;
        int r = off >> 7, cb = off & 127;
        ra[it] = *(const u32x4*)(Ag + (size_t)(o0 + r) * 1024 + (kt + 1) * 128 + cb);
        rb[it] = *(const u32x4*)(Bg + (size_t)r * 1024 + (kt + 1) * 128 + cb);
      }
    }
#pragma unroll
    for (int kk = 0; kk < 4; ++kk) {
      int csw = (kk * 32 + hi * 16) ^ ((ln & 7) << 4);
      bfrag a[2], bb[2];
#pragma unroll
      for (int m2 = 0; m2 < 2; ++m2)
        a[m2] = *(const bfrag*)(ldsA + (wr * 64 + m2 * 32 + ln) * 128 + csw);
#pragma unroll
      for (int n2 = 0; n2 < 2; ++n2)
        bb[n2] = *(const bfrag*)(ldsB + (wc * 64 + n2 * 32 + ln) * 128 + csw);
#pragma unroll
      for (int m2 = 0; m2 < 2; ++m2)
#pragma unroll
        for (int n2 = 0; n2 < 2; ++n2)
          acc[m2][n2] = __builtin_amdgcn_mfma_f32_32x32x16_bf16(a[m2], bb[n2], acc[m2][n2], 0, 0, 0);
    }
  }

#pragma unroll
  for (int m2 = 0; m2 < 2; ++m2) {
    int obase = o0 + wr * 64 + m2 * 32;
#pragma unroll
    for (int n2 = 0; n2 < 2; ++n2) {
      int t = t0 + wc * 64 + n2 * 32 + ln;
#pragma unroll
      for (int r = 0; r < 16; ++r) {
        int o = obase + (r & 3) + 8 * (r >> 2) + 4 * hi;
        Yout[(((size_t)b * C_SZ + o) << 10) + t] = acc[m2][n2][r] + bp[o];
      }
    }
  }
}

// ---- fused flash attention, in-block s-split (8 waves: grp0 s<512, grp1 s>=512)
// Qf/Kf: [bh][tile32][j:4][lane:64][8] bf16; Vf: [bh][stile][fi:4][lane:64][8]
// mbT: [b][s/32][t]. Q already scaled by 1/(sqrt(dk)*ln2) -> exp2-domain softmax.
// Grid: n = tb*64 + bh => n%8 == bh%8: all t-blocks of one (b,h) on one XCD.
__launch_bounds__(512, 4)
__global__ void attn_fused(const u16* __restrict__ Qf, const u16* __restrict__ Kf,
                           const u16* __restrict__ Vf, const u32* __restrict__ mbT,
                           u16* __restrict__ X2) {
  __shared__ __align__(16) char smem[33 * 1024];
  u16*   sK   = (u16*)smem;             // [grp:2][buf:2][2048] = 16 KB
  u16*   sV   = (u16*)(smem + 16384);   // [grp:2][buf:2][2048] = 16 KB
  float* comb = (float*)smem;           // aliases sK/sV: 4*2048 f32 = 32 KB (used post-loop)
  float* mlb  = (float*)(smem + 32768); // 4*32*2 f32 = 1 KB

  int n = blockIdx.x;
  int bh = n & 63, tb = n >> 6;
  int b = bh >> 3, h = bh & 7;
  int tid = threadIdx.x;
  int wid = tid >> 6, lane = tid & 63;
  int grp = wid >> 2, wl = wid & 3;
  int ln = lane & 31, hi = lane >> 5;
  int tt = tb * 4 + wl;
  int t  = tt * 32 + ln;

  // Q fragments: one coalesced 1KB load per j
  const u16* QfT = Qf + (((size_t)bh * 32 + tt) << 11);
  bfrag qf[4];
#pragma unroll
  for (int j = 0; j < 4; ++j)
    qf[j] = *(const bfrag*)(QfT + j * 512 + lane * 8);

  const u16* KfB = Kf + ((size_t)bh << 16);
  const u16* VfB = Vf + ((size_t)bh << 16);
  const u32* mcol = mbT + ((size_t)b << 15) + t;

  // m_run floor -1e4 (not -1e30): masked scores stay -1e30, so
  // exp2(-1e30 - m_run) == +0 in HW -> no post-exp mask pass needed.
  // Fully-masked rows: m_run never raised, l_run stays 0 -> invl=0 -> zeros.
  float m_run = -1.0e4f, l_run = 0.f;
  accfrag accd[2];
#pragma unroll
  for (int m2 = 0; m2 < 2; ++m2)
#pragma unroll
    for (int e = 0; e < 16; ++e) accd[m2][e] = 0.f;

  int gtid = tid & 255;
  int soff = gtid * 8;                      // u16 offset: 16B per thread, per 4-wave group
  u16* sKg = sK + grp * 4096;               // this group's [buf][2048]
  u16* sVg = sV + grp * 4096;
  int st0 = grp * 16;

  // prologue: stage this group's tile 0, load mask word
  gload16(KfB + ((size_t)st0 << 11) + soff, sKg + soff);
  gload16(VfB + ((size_t)st0 << 11) + soff, sVg + soff);
  u32 mw = mcol[st0 << 10];
  __syncthreads();

#pragma unroll 2
  for (int it = 0; it < 16; ++it) {
    int cur = it & 1, nxt = cur ^ 1;
    int st = st0 + it;
    u32 mn = 0;
    if (it < 15) {   // stage next tile; latency spans the whole compute phase
      size_t tn = (size_t)(st + 1) << 11;
      gload16(KfB + tn + soff, sKg + nxt * 2048 + soff);
      gload16(VfB + tn + soff, sVg + nxt * 2048 + soff);
      mn = mcol[(st + 1) << 10];
    }

    // fragments from LDS (lane-linear -> conflict-free b128 reads)
    bfrag kf[4], vf[4];
#pragma unroll
    for (int j = 0; j < 4; ++j) {
      kf[j] = *(const bfrag*)(sKg + cur * 2048 + j * 512 + lane * 8);
      vf[j] = *(const bfrag*)(sVg + cur * 2048 + j * 512 + lane * 8);
    }

    // QK^T (S already in log2 units: Q pre-scaled)
    accfrag S;
#pragma unroll
    for (int e = 0; e < 16; ++e) S[e] = 0.f;
#pragma unroll
    for (int j = 0; j < 4; ++j)
      S = __builtin_amdgcn_mfma_f32_32x32x16_bf16(kf[j], qf[j], S, 0, 0, 0);

    // ---- softmax over key rows (per-lane: 16 of 32 rows; partner lane^32)
    u32 mbits = mw >> (4 * hi);          // bit positions now compile-time per r
    float p[16];
#pragma unroll
    for (int r = 0; r < 16; ++r) {
      int pos = (r & 3) + 8 * (r >> 2);  // const -> v_bfe + cndmask
      p[r] = ((mbits >> pos) & 1u) ? S[r] : -1e30f;
    }
    float q8[8], q4[4];
#pragma unroll
    for (int r = 0; r < 8; ++r) q8[r] = fmaxf(p[r], p[r + 8]);
#pragma unroll
    for (int r = 0; r < 4; ++r) q4[r] = fmaxf(q8[r], q8[r + 4]);
    float pmax = fmaxf(fmaxf(q4[0], q4[1]), fmaxf(q4[2], q4[3]));
    pmax = fmaxf(pmax, __shfl_xor(pmax, 32));

    // deferred rescale (T13): 8 nats = 11.54 bits
    if (__any(pmax > m_run + 11.5f)) {
      float m_new = fmaxf(m_run, pmax);
      float alpha = fexp2(m_run - m_new);
      l_run *= alpha;
#pragma unroll
      for (int m2 = 0; m2 < 2; ++m2)
#pragma unroll
        for (int e = 0; e < 16; ++e) accd[m2][e] *= alpha;
      m_run = m_new;
    }

#pragma unroll
    for (int r = 0; r < 16; ++r)
      p[r] = fexp2(p[r] - m_run);        // masked: exp2(-1e30) == +0
    float s8[8], s4[4];
#pragma unroll
    for (int r = 0; r < 8; ++r) s8[r] = p[r] + p[r + 8];
#pragma unroll
    for (int r = 0; r < 4; ++r) s4[r] = s8[r] + s8[r + 4];
    float psum = (s4[0] + s4[1]) + (s4[2] + s4[3]);
    psum += __shfl_xor(psum, 32);
    l_run += psum;

    // P (D-layout) -> B-operand bf16 frags: 8 cvt_pk + 4 permlane32_swap
    bfrag pf[2];
#pragma unroll
    for (int j2 = 0; j2 < 2; ++j2) {
      u32 A0 = cvtpk(p[8 * j2 + 0], p[8 * j2 + 1]);
      u32 A1 = cvtpk(p[8 * j2 + 2], p[8 * j2 + 3]);
      u32 B0 = cvtpk(p[8 * j2 + 4], p[8 * j2 + 5]);
      u32 B1 = cvtpk(p[8 * j2 + 6], p[8 * j2 + 7]);
      permswap(A0, B0);
      permswap(A1, B1);
      union { u32 u[4]; bfrag f; } pu;
      pu.u[0] = A0; pu.u[1] = A1; pu.u[2] = B0; pu.u[3] = B1;
      pf[j2] = pu.f;
    }
#pragma unroll
    for (int j2 = 0; j2 < 2; ++j2)
#pragma unroll
      for (int m2 = 0; m2 < 2; ++m2)
        accd[m2] = __builtin_amdgcn_mfma_f32_32x32x16_bf16(vf[j2 * 2 + m2], pf[j2], accd[m2], 0, 0, 0);

    __syncthreads();   // drains stage DMA + LDS reads; swap buffers
    mw = mn;
  }

  // ---- merge the two s-halves through LDS (comb aliases staging buffers) --
  if (grp == 1) {
#pragma unroll
    for (int m2 = 0; m2 < 2; ++m2)
#pragma unroll
      for (int e = 0; e < 16; ++e)
        comb[wl * 2048 + (m2 * 16 + e) * 64 + lane] = accd[m2][e];
    if (hi == 0) {
      mlb[(wl * 32 + ln) * 2]     = m_run;
      mlb[(wl * 32 + ln) * 2 + 1] = l_run;
    }
  }
  __syncthreads();
  if (grp == 0) {
    float m1v = mlb[(wl * 32 + ln) * 2];
    float l1v = mlb[(wl * 32 + ln) * 2 + 1];
    float M  = fmaxf(m_run, m1v);
    float w0 = fexp2(m_run - M), w1 = fexp2(m1v - M);
    float l  = l_run * w0 + l1v * w1;
    float invl = (l > 0.f) ? 1.f / l : 0.f;
    u16* Orow = X2 + (((size_t)b << 10) + t) * C_SZ + h * DK;
#pragma unroll
    for (int m2 = 0; m2 < 2; ++m2)
#pragma unroll
      for (int g = 0; g < 4; ++g) {
        u16x4 pk4;
#pragma unroll
        for (int qq = 0; qq < 4; ++qq) {
          int e = 4 * g + qq;
          float v2 = comb[wl * 2048 + (m2 * 16 + e) * 64 + lane];
          pk4[qq] = f2bf((accd[m2][e] * w0 + v2 * w1) * invl);
        }
        *(u16x4*)(Orow + m2 * 32 + 8 * g + 4 * hi) = pk4;
      }
  }
}

extern "C" void kernel_launch(void* const* d_in, const int* in_sizes, int n_in,
                              void* d_out, int out_size, void* d_ws, size_t ws_size,
                              hipStream_t stream) {
  (void)in_sizes; (void)n_in; (void)out_size; (void)ws_size;
  const float* q    = (const float*)d_in[0];
  const float* k    = (const float*)d_in[1];
  const float* v    = (const float*)d_in[2];
  const int*   mask = (const int*)d_in[3];
  const float* Ws   = (const float*)d_in[4];
  const float* bs   = (const float*)d_in[5];
  const float* gam  = (const float*)d_in[6];
  const float* beta = (const float*)d_in[7];
  const float* mean = (const float*)d_in[8];
  const float* var  = (const float*)d_in[9];

  float* out   = (float*)d_out;
  float* cache = out + (size_t)B_SZ * C_SZ * T_SZ;     // 4,194,304 floats

  const size_t ARR = (size_t)B_SZ * T_SZ * C_SZ;       // 4,194,304 elems
  char* ws = (char*)d_ws;
  u16*   Wp = (u16*)(ws);                              // 4*512*512 bf16 = 2 MB
  float* bp = (float*)(ws + 2097152);                  // 2048 f32
  u16*   Xt = (u16*)(ws + 2162688);                    // 3 * ARR bf16
  u16*   Qt = Xt + 3 * ARR;                            // Qf fragment layout
  u16*   Kt = Qt + ARR;                                // Kf fragment layout
  u16*   Vb = Kt + ARR;                                // Vf fragment layout
  u16*   X2 = Vb + ARR;
  u32*   mb = (u32*)((char*)(X2 + ARR));               // 262144 words = 1 MB

  prep_w<<<4096, 256, 0, stream>>>(Ws, gam, var, Wp);
  prep_b<<<8, 256, 0, stream>>>(bs, gam, beta, mean, var, bp);
  transpose_cvt<<<dim3(32, 16, 24), 256, 0, stream>>>(q, k, v, Xt, cache);
  mask_bits<<<1024, 256, 0, stream>>>(mask, mb);

  gemm_qkv<<<dim3(8, 4, 24), 256, 0, stream>>>(Wp, bp, Xt, Qt, Kt, Vb);
  attn_fused<<<512, 512, 0, stream>>>(Qt, Kt, Vb, mb, X2);
  gemm_out<<<dim3(8, 4, 8), 256, 0, stream>>>(Wp + 786432, bp + 1536, X2, out);
}